// Round 6
// baseline (962.055 us; speedup 1.0000x reference)
//
#include <hip/hip_runtime.h>

#define HDIM 128
#define TTOK 8
#define NPG 1024
#define NBUCK 512
#define BSHIFT 8
#define BCAP 5120
#define EPB 4096
#define PARTSZ 4160   // per (graph,part): 32*128 O + 32 m + 32 l

// MW (transposed mamba weights) section offsets, in floats
#define MW_WVT 0         // [2][128][128]  WvT[l][col][c] = qkv_w[l][c*384+256+col]
#define MW_AOT 32768     // [2][128][128]  aoT[l][col][k] = ao_w[l][k*128+col]
#define MW_INT 65536     // [512][128]     inT[j][c] = in_w[c*512+j]
#define MW_XT  131072    // [40][256]      xT[j][c]  = x_w[c*40+j]
#define MW_DTT 141312    // [256][8]       dtT[i][r] = dt_w[r*256+i]
#define MW_OUT 143360    // [128][256]     outT[c][i]= out_w[i*128+c]
#define MW_TOT 176128

typedef unsigned short ushort;
typedef unsigned int uint;
typedef __attribute__((ext_vector_type(8))) short short8;
typedef __attribute__((ext_vector_type(4))) float f32x4;

__device__ __forceinline__ ushort f2bf(float f) {
    unsigned int x = __float_as_uint(f);
    return (ushort)((x + 0x7FFFu + ((x >> 16) & 1u)) >> 16);
}
__device__ __forceinline__ float blo(uint u) { return __uint_as_float(u << 16); }
__device__ __forceinline__ float bhi(uint u) { return __uint_as_float(u & 0xFFFF0000u); }
__device__ __forceinline__ uint pk(float a, float b) {
    return (uint)f2bf(a) | ((uint)f2bf(b) << 16);
}

// ================= bin body (mode 0: key=dst pay=src; mode 1: key=src pay=graph(dst)) =================
__device__ __forceinline__ void bin_body(const int* __restrict__ src,
    const int* __restrict__ dst, int mode, int* __restrict__ bcursor,
    uint* __restrict__ pairbuf, int E, int e0, int tid,
    int* lcnt, int* lbase)
{
    for (int i = tid; i < NBUCK; i += 256) lcnt[i] = 0;
    __syncthreads();
    uint pkd[16];
    int bk[16], rk[16];
    #pragma unroll
    for (int i = 0; i < 16; ++i) {
        int e = e0 + i * 256 + tid;
        int s = (e < E) ? src[e] : 0;
        int d = (e < E) ? dst[e] : 0;
        int key = mode ? s : d;
        uint pay = mode ? (uint)(d >> 10) : (uint)s;
        if (e >= E) key = -1;
        int b = key >> BSHIFT;
        bk[i] = b;
        pkd[i] = ((uint)(key & 255) << 17) | pay;
        rk[i] = (key >= 0) ? atomicAdd(&lcnt[b], 1) : 0;
    }
    __syncthreads();
    for (int i = tid; i < NBUCK; i += 256) {
        int c = lcnt[i];
        lbase[i] = c ? atomicAdd(&bcursor[i], c) : 0;
    }
    __syncthreads();
    #pragma unroll
    for (int i = 0; i < 16; ++i) {
        if (bk[i] >= 0) {
            int slot = lbase[bk[i]] + rk[i];
            if (slot < BCAP) pairbuf[(size_t)bk[i] * BCAP + slot] = pkd[i];
        }
    }
}

// ================= dst-bin + f32->bf16 convert, one launch =================
// blocks [0,512): bin dst; blocks [512, 512+2048): grid-stride convert
__global__ __launch_bounds__(256) void bin_conv_kernel(const int* __restrict__ src,
    const int* __restrict__ dst, int* __restrict__ bcursor, uint* __restrict__ pairbuf,
    int E, const float* __restrict__ xin, ushort* __restrict__ outb, int n4)
{
    __shared__ int lcnt[NBUCK];
    __shared__ int lbase[NBUCK];
    int tid = threadIdx.x;
    int b = blockIdx.x;
    if (b < NBUCK) {
        bin_body(src, dst, 0, bcursor, pairbuf, E, b * EPB, tid, lcnt, lbase);
    } else {
        for (int i = (b - NBUCK) * 256 + tid; i < n4; i += 2048 * 256) {
            float4 v = ((const float4*)xin)[i];
            uint2 o;
            o.x = pk(v.x, v.y); o.y = pk(v.z, v.w);
            ((uint2*)outb)[i] = o;
        }
    }
}

// ================= Pass B (dst-sort): one block per bucket; self-scans bucket counts =================
__global__ __launch_bounds__(256) void bucket_sort_kernel(const uint* __restrict__ pairbuf,
    const int* __restrict__ bcount,
    int* __restrict__ ssrc, int* __restrict__ starts, int* __restrict__ countn, int N)
{
    __shared__ int sc[NBUCK];
    __shared__ int lcount[256];
    __shared__ int lcur[256];
    __shared__ int lss[BCAP];   // 20 KB
    int b = blockIdx.x;
    int tid = threadIdx.x;
    sc[tid] = min(bcount[tid], BCAP);
    sc[tid + 256] = min(bcount[tid + 256], BCAP);
    lcount[tid] = 0;
    __syncthreads();
    for (int off = 1; off < NBUCK; off <<= 1) {
        int a0 = (tid >= off) ? sc[tid - off] : 0;
        int a1 = (tid + 256 >= off) ? sc[tid + 256 - off] : 0;
        __syncthreads();
        sc[tid] += a0; sc[tid + 256] += a1;
        __syncthreads();
    }
    int nb = min(bcount[b], BCAP);
    int base = sc[b] - nb;
    const uint* pp = pairbuf + (size_t)b * BCAP;
    for (int i = tid; i < nb; i += 256)
        atomicAdd(&lcount[(pp[i] >> 17) & 255], 1);
    __syncthreads();
    int v = lcount[tid];
    lcur[tid] = v;
    __syncthreads();
    for (int off = 1; off < 256; off <<= 1) {
        int t = (tid >= off) ? lcur[tid - off] : 0;
        __syncthreads();
        lcur[tid] += t;
        __syncthreads();
    }
    int excl = lcur[tid] - v;
    int node = b * 256 + tid;
    starts[node] = base + excl;
    countn[node] = v;
    __syncthreads();
    lcur[tid] = excl;
    __syncthreads();
    for (int i = tid; i < nb; i += 256) {
        uint p = pp[i];
        int pos = atomicAdd(&lcur[(p >> 17) & 255], 1);
        lss[pos] = (int)(p & 0x1FFFFu);
    }
    __syncthreads();
    for (int i = tid; i < nb; i += 256) ssrc[base + i] = lss[i];
    if (b == NBUCK - 1 && tid == 0) starts[N] = base + nb;
}

// ================= prep: attn P (blocks 0-1) + weight transposes (2-689) + src-bin (690-1201) =================
__global__ __launch_bounds__(256) void prep_binsrc_kernel(const float* __restrict__ vt,
    const float* __restrict__ qkv_w, const float* __restrict__ qkv_b, float* __restrict__ P,
    const float* __restrict__ ao_w, const float* __restrict__ in_w,
    const float* __restrict__ x_w, const float* __restrict__ dt_w,
    const float* __restrict__ out_w, float* __restrict__ MW,
    const int* __restrict__ src, const int* __restrict__ dst,
    int* __restrict__ bcursor2, uint* __restrict__ pairbuf, int E)
{
    __shared__ float vtl[TTOK][HDIM];
    __shared__ float q[TTOK][HDIM];
    __shared__ int lcnt[NBUCK];
    __shared__ int lbase[NBUCK];
    int b = blockIdx.x, tid = threadIdx.x;
    if (b < 2) {
        int l = b;
        const float* vtp = vt + (size_t)l * TTOK * HDIM;
        const float* qw = qkv_w + (size_t)l * 128 * 384;
        const float* qb = qkv_b + (size_t)l * 384;
        float* Pp = P + (size_t)l * 4 * TTOK * HDIM;
        for (int i = tid; i < TTOK * HDIM; i += 256) vtl[i >> 7][i & 127] = vtp[i];
        __syncthreads();
        for (int i = tid; i < TTOK * HDIM; i += 256) {
            int t = i >> 7, j = i & 127;
            float acc = qb[j];
            for (int c = 0; c < 128; ++c) acc += vtl[t][c] * qw[c * 384 + j];
            q[t][j] = acc;
        }
        __syncthreads();
        const float scale = 0.17677669529663687f; // 1/sqrt(32)
        for (int i = tid; i < 4 * TTOK * HDIM; i += 256) {
            int h = i >> 10, t = (i >> 7) & 7, cc = i & 127;
            float acc = 0.f;
            for (int d = 0; d < 32; ++d)
                acc += qw[cc * 384 + 128 + h * 32 + d] * q[t][h * 32 + d];
            Pp[i] = acc * scale;
        }
    } else if (b < 690) {
        int idx = (b - 2) * 256 + tid;
        float v;
        if (idx < 32768) {            // WvT
            int l = idx >> 14, o = idx & 16383, col = o >> 7, c = o & 127;
            v = qkv_w[(size_t)l * 49152 + c * 384 + 256 + col];
        } else if (idx < 65536) {     // aoT
            int t = idx - 32768; int l = t >> 14, o = t & 16383, col = o >> 7, k = o & 127;
            v = ao_w[(size_t)l * 16384 + k * 128 + col];
        } else if (idx < 131072) {    // inT
            int t = idx - 65536; int j = t >> 7, c = t & 127;
            v = in_w[c * 512 + j];
        } else if (idx < 141312) {    // xT
            int t = idx - 131072; int j = t >> 8, c = t & 255;
            v = x_w[c * 40 + j];
        } else if (idx < 143360) {    // dtT
            int t = idx - 141312; int i = t >> 3, r = t & 7;
            v = dt_w[r * 256 + i];
        } else {                      // outT
            int t = idx - 143360; int c = t >> 8, i = t & 255;
            v = out_w[i * 128 + c];
        }
        MW[idx] = v;
    } else {
        bin_body(src, dst, 1, bcursor2, pairbuf, E, (b - 690) * EPB, tid, lcnt, lbase);
    }
}

// ================= gather body: 16 nodes, 16 lanes each, 8-deep ILP =================
__device__ __forceinline__ void gather16_body(const ushort* __restrict__ XS,
    const int* __restrict__ ssrc, const int* __restrict__ starts,
    const int* __restrict__ count, ushort* __restrict__ AGG, int nbase, int tid)
{
    int g = tid >> 4, lane = tid & 15;
    int node = nbase + g;
    uint4 sv = *((const uint4*)(XS + (size_t)node * HDIM) + lane);
    float a0 = blo(sv.x), a1 = bhi(sv.x), a2 = blo(sv.y), a3 = bhi(sv.y);
    float a4 = blo(sv.z), a5 = bhi(sv.z), a6 = blo(sv.w), a7 = bhi(sv.w);
    int s0 = starts[node], cn = count[node];
    for (int j0 = 0; j0 < cn; j0 += 16) {
        int myid = (j0 + lane < cn) ? ssrc[s0 + j0 + lane] : 0;
        int m = min(16, cn - j0);
        int j = 0;
        for (; j + 7 < m; j += 8) {
            uint4 u[8];
            #pragma unroll
            for (int q = 0; q < 8; ++q) {
                int sidx = __shfl(myid, j + q, 16);
                u[q] = *((const uint4*)(XS + (size_t)sidx * HDIM) + lane);
            }
            #pragma unroll
            for (int q = 0; q < 8; ++q) {
                a0 += blo(u[q].x); a1 += bhi(u[q].x);
                a2 += blo(u[q].y); a3 += bhi(u[q].y);
                a4 += blo(u[q].z); a5 += bhi(u[q].z);
                a6 += blo(u[q].w); a7 += bhi(u[q].w);
            }
        }
        for (; j + 3 < m; j += 4) {
            uint4 u[4];
            #pragma unroll
            for (int q = 0; q < 4; ++q) {
                int sidx = __shfl(myid, j + q, 16);
                u[q] = *((const uint4*)(XS + (size_t)sidx * HDIM) + lane);
            }
            #pragma unroll
            for (int q = 0; q < 4; ++q) {
                a0 += blo(u[q].x); a1 += bhi(u[q].x);
                a2 += blo(u[q].y); a3 += bhi(u[q].y);
                a4 += blo(u[q].z); a5 += bhi(u[q].z);
                a6 += blo(u[q].w); a7 += bhi(u[q].w);
            }
        }
        for (; j < m; ++j) {
            int sidx = __shfl(myid, j, 16);
            uint4 ua = *((const uint4*)(XS + (size_t)sidx * HDIM) + lane);
            a0 += blo(ua.x); a1 += bhi(ua.x);
            a2 += blo(ua.y); a3 += bhi(ua.y);
            a4 += blo(ua.z); a5 += bhi(ua.z);
            a6 += blo(ua.w); a7 += bhi(ua.w);
        }
    }
    uint4 o;
    o.x = pk(a0, a1); o.y = pk(a2, a3); o.z = pk(a4, a5); o.w = pk(a6, a7);
    *((uint4*)(AGG + (size_t)node * HDIM) + lane) = o;
}

// ================= standalone gather (input GIN; nothing to overlap) =================
__global__ __launch_bounds__(256) void gather_kernel(const ushort* __restrict__ XS,
    const int* __restrict__ ssrc, const int* __restrict__ starts,
    const int* __restrict__ count, ushort* __restrict__ AGG)
{
    gather16_body(XS, ssrc, starts, count, AGG, blockIdx.x * 16, threadIdx.x);
}

// ================= attention body v3: 64-node tiles, ~25.2 KB LDS (St/P union) =================
__device__ __forceinline__ void attn_body(const ushort* __restrict__ X,
    const float* __restrict__ P, float* __restrict__ PART, int bp, int tid)
{
    __shared__ ushort Xl[64 * 128];    // 16 KB swizzled X tile (64 nodes)
    __shared__ float  StU[32 * 68];    // 8.5 KB union: prologue-P bf16 / scores f32 / exp-P bf16
    __shared__ float lm[32], ll[32], lalpha[32];
    ushort* PlU = (ushort*)StU;
    int b = bp >> 2, part = bp & 3;
    int wave = tid >> 6, lane = tid & 63;
    int m16 = lane & 15, quad = lane >> 4;

    for (int i = tid; i < 2048; i += 256) {
        float2 v = *(const float2*)(P + (size_t)i * 2);
        ((uint*)PlU)[i] = pk(v.x, v.y);
    }
    if (tid < 32) { lm[tid] = -1e30f; ll[tid] = 0.f; }
    __syncthreads();
    short8 aP[2][4];
    #pragma unroll
    for (int mt = 0; mt < 2; ++mt)
        #pragma unroll
        for (int kc = 0; kc < 4; ++kc)
            aP[mt][kc] = *(const short8*)&PlU[(mt * 16 + m16) * 128 + (kc * 4 + quad) * 8];
    __syncthreads();

    f32x4 oacc[2][2] = {};
    const uint4* xsg = (const uint4*)(X + (size_t)b * NPG * HDIM);

    for (int tt = 0; tt < 4; ++tt) {
        // ---- stage 64-node tile ----
        {
            const uint4* xs = xsg + (part * 4 + tt) * 1024;
            uint4* xl = (uint4*)Xl;
            for (int i = tid; i < 1024; i += 256) {
                int row = i >> 4, cc = i & 15;
                xl[row * 16 + (cc ^ (row & 15))] = xs[i];
            }
        }
        __syncthreads();
        // ---- QK^T: S[32 t][64 n] into StU ----
        {
            f32x4 sacc[2] = {};
            #pragma unroll
            for (int kc = 0; kc < 4; ++kc) {
                int node = wave * 16 + m16;
                short8 bx = *(const short8*)&Xl[node * 128 + (((kc * 4 + quad) ^ m16) << 3)];
                sacc[0] = __builtin_amdgcn_mfma_f32_16x16x32_bf16(aP[0][kc], bx, sacc[0], 0, 0, 0);
                sacc[1] = __builtin_amdgcn_mfma_f32_16x16x32_bf16(aP[1][kc], bx, sacc[1], 0, 0, 0);
            }
            #pragma unroll
            for (int mt = 0; mt < 2; ++mt)
                #pragma unroll
                for (int r = 0; r < 4; ++r)
                    StU[(mt * 16 + quad * 4 + r) * 68 + wave * 16 + m16] = sacc[mt][r];
        }
        __syncthreads();
        // ---- online softmax over this 64-node tile ----
        {
            int j = tid >> 3, g = tid & 7;
            const float* rowp = &StU[j * 68 + g * 8];
            float4 v0 = *(const float4*)(rowp);
            float4 v1 = *(const float4*)(rowp + 4);
            float mx = fmaxf(fmaxf(fmaxf(v0.x, v0.y), fmaxf(v0.z, v0.w)),
                             fmaxf(fmaxf(v1.x, v1.y), fmaxf(v1.z, v1.w)));
            mx = fmaxf(mx, __shfl_down(mx, 4, 8));
            mx = fmaxf(mx, __shfl_down(mx, 2, 8));
            mx = fmaxf(mx, __shfl_down(mx, 1, 8));
            mx = __shfl(mx, 0, 8);
            float mold = lm[j];
            float Mn = fmaxf(mold, mx);
            float alpha = __expf(mold - Mn);
            float p0 = __expf(v0.x - Mn), p1 = __expf(v0.y - Mn);
            float p2 = __expf(v0.z - Mn), p3 = __expf(v0.w - Mn);
            float p4 = __expf(v1.x - Mn), p5 = __expf(v1.y - Mn);
            float p6 = __expf(v1.z - Mn), p7 = __expf(v1.w - Mn);
            float s = ((p0 + p1) + (p2 + p3)) + ((p4 + p5) + (p6 + p7));
            s += __shfl_down(s, 4, 8);
            s += __shfl_down(s, 2, 8);
            s += __shfl_down(s, 1, 8);
            if (g == 0) {
                ll[j] = ll[j] * alpha + s;
                lm[j] = Mn;
                lalpha[j] = alpha;
            }
            __syncthreads();   // all St reads complete before exp-P overwrites the union
            uint4 u0;
            u0.x = pk(p0, p1); u0.y = pk(p2, p3); u0.z = pk(p4, p5); u0.w = pk(p6, p7);
            ((uint4*)PlU)[j * 8 + (g ^ (j & 7))] = u0;   // exp-P [32][64], chunk-swizzled
        }
        __syncthreads();
        // ---- PV accumulate ----
        {
            #pragma unroll
            for (int mt = 0; mt < 2; ++mt)
                #pragma unroll
                for (int r = 0; r < 4; ++r) {
                    float a = lalpha[mt * 16 + quad * 4 + r];
                    oacc[mt][0][r] *= a;
                    oacc[mt][1][r] *= a;
                }
            #pragma unroll
            for (int kc = 0; kc < 2; ++kc) {
                short8 ap2[2], bx[2];
                #pragma unroll
                for (int mt = 0; mt < 2; ++mt)
                    ap2[mt] = *(const short8*)&PlU[(mt * 16 + m16) * 64
                                                   + (((kc * 4 + quad) ^ (m16 & 7)) << 3)];
                #pragma unroll
                for (int ntl = 0; ntl < 2; ++ntl) {
                    int cf = (2 * wave + ntl) * 16 + m16;
                    int chi = cf >> 3, clo = cf & 7;
                    short8 v;
                    #pragma unroll
                    for (int jj = 0; jj < 8; ++jj) {
                        int row = kc * 32 + quad * 8 + jj;
                        v[jj] = (short)Xl[(row << 7) + ((chi ^ (row & 15)) << 3) + clo];
                    }
                    bx[ntl] = v;
                }
                #pragma unroll
                for (int mt = 0; mt < 2; ++mt)
                    #pragma unroll
                    for (int ntl = 0; ntl < 2; ++ntl)
                        oacc[mt][ntl] = __builtin_amdgcn_mfma_f32_16x16x32_bf16(
                            ap2[mt], bx[ntl], oacc[mt][ntl], 0, 0, 0);
            }
        }
        __syncthreads();
    }
    float* PB = PART + ((size_t)b * 4 + part) * PARTSZ;
    #pragma unroll
    for (int mt = 0; mt < 2; ++mt)
        #pragma unroll
        for (int r = 0; r < 4; ++r) {
            int j = mt * 16 + quad * 4 + r;
            PB[j * 128 + (2 * wave + 0) * 16 + m16] = oacc[mt][0][r];
            PB[j * 128 + (2 * wave + 1) * 16 + m16] = oacc[mt][1][r];
        }
    if (tid < 32) { PB[4096 + tid] = lm[tid]; PB[4128 + tid] = ll[tid]; }
}

// ================= combined attention ∥ gather (independent work, one dispatch) =================
__global__ __launch_bounds__(256) void attn_gather_kernel(const ushort* __restrict__ X,
    const float* __restrict__ P, float* __restrict__ PART,
    const int* __restrict__ ssrc, const int* __restrict__ starts,
    const int* __restrict__ count, ushort* __restrict__ AGG)
{
    int bp = blockIdx.x;
    if (bp % 17 == 0) {
        attn_body(X, P, PART, bp / 17, threadIdx.x);
    } else {
        int gidx = bp - bp / 17 - 1;
        gather16_body(X, ssrc, starts, count, AGG, gidx * 16, threadIdx.x);
    }
}

// ================= MFMA linear (bf16 in/out): XD = XS @ W + b [+ GF[row>>10]] =================
__global__ __launch_bounds__(256) void lin128_mfma_kernel(const ushort* __restrict__ XS,
    const float* __restrict__ W, const float* __restrict__ bias,
    const float* __restrict__ GF, ushort* __restrict__ XD)
{
    __shared__ ushort Xl[128 * 128];
    __shared__ ushort Wl[128 * 128];
    int tid = threadIdx.x;
    size_t r0 = (size_t)blockIdx.x * 128;
    {
        const uint4* xs = (const uint4*)(XS + r0 * HDIM);
        uint4* xl = (uint4*)Xl;
        for (int i = tid; i < 2048; i += 256) {
            int row = i >> 4, cc = i & 15;
            xl[row * 16 + (cc ^ (row & 15))] = xs[i];
        }
    }
    {
        uint4* wl = (uint4*)Wl;
        for (int i = tid; i < 2048; i += 256) {
            int n = i & 127, c = i >> 7;
            const float* wp = W + (size_t)(c * 8) * 128 + n;
            float w0 = wp[0], w1 = wp[128], w2 = wp[256], w3 = wp[384];
            float w4 = wp[512], w5 = wp[640], w6 = wp[768], w7 = wp[896];
            uint4 u;
            u.x = pk(w0, w1); u.y = pk(w2, w3); u.z = pk(w4, w5); u.w = pk(w6, w7);
            wl[n * 16 + (c ^ (n & 15))] = u;
        }
    }
    __syncthreads();
    int wave = tid >> 6;
    int lane = tid & 63;
    int m16 = lane & 15, quad = lane >> 4;
    const short8* Xf = (const short8*)Xl;
    const short8* Wf = (const short8*)Wl;
    short8 afr[2][4];
    #pragma unroll
    for (int rt = 0; rt < 2; ++rt)
        #pragma unroll
        for (int kc = 0; kc < 4; ++kc)
            afr[rt][kc] = Xf[(wave * 32 + rt * 16 + m16) * 16 + ((kc * 4 + quad) ^ m16)];
    int graph = (int)(r0 >> 10);
    #pragma unroll
    for (int ct = 0; ct < 8; ++ct) {
        int col = ct * 16 + m16;
        short8 bfr[4];
        #pragma unroll
        for (int kc = 0; kc < 4; ++kc)
            bfr[kc] = Wf[col * 16 + ((kc * 4 + quad) ^ m16)];
        f32x4 acc0 = {0.f, 0.f, 0.f, 0.f};
        f32x4 acc1 = {0.f, 0.f, 0.f, 0.f};
        #pragma unroll
        for (int kc = 0; kc < 4; ++kc) {
            acc0 = __builtin_amdgcn_mfma_f32_16x16x32_bf16(afr[0][kc], bfr[kc], acc0, 0, 0, 0);
            acc1 = __builtin_amdgcn_mfma_f32_16x16x32_bf16(afr[1][kc], bfr[kc], acc1, 0, 0, 0);
        }
        float add = bias[col] + (GF ? GF[(size_t)graph * HDIM + col] : 0.f);
        #pragma unroll
        for (int r = 0; r < 4; ++r) {
            XD[(r0 + wave * 32 + quad * 4 + r) * HDIM + col] = f2bf(acc0[r] + add);
            XD[(r0 + wave * 32 + 16 + quad * 4 + r) * HDIM + col] = f2bf(acc1[r] + add);
        }
    }
}

// ================= mamba: transposed weights (MW), contiguous float4 streams =================
__global__ __launch_bounds__(1024) void mamba_kernel(const float* __restrict__ PART,
    const float* __restrict__ qkv_b, const float* __restrict__ ao_b,
    const float* __restrict__ MW, int l,
    const float* __restrict__ conv_w, const float* __restrict__ conv_b,
    const float* __restrict__ dt_b, const float* __restrict__ A_log,
    const float* __restrict__ Dp, const float* __restrict__ norm_w,
    const float* __restrict__ normf_w, float* __restrict__ GF)
{
    constexpr int I = 256, S = 16;
    __shared__ float R[32 * 132];
    __shared__ float wgt[4][32];
    __shared__ float inv[32];
    __shared__ float tok[TTOK][HDIM];
    __shared__ float hn[TTOK][HDIM];
    __shared__ float uu[TTOK][I];
    __shared__ float gg[TTOK][I];
    __shared__ float ssm[TTOK][40];
    __shared__ float yy[TTOK][I];
    int b = blockIdx.x, tid = threadIdx.x;

    // ---- fused attention merge: PART -> R ----
    const float* PB = PART + (size_t)b * 4 * PARTSZ;
    if (tid < 32) {
        int j = tid;
        float m0 = PB[4096 + j], m1 = PB[PARTSZ + 4096 + j];
        float m2 = PB[2 * PARTSZ + 4096 + j], m3 = PB[3 * PARTSZ + 4096 + j];
        float M = fmaxf(fmaxf(m0, m1), fmaxf(m2, m3));
        float w0 = __expf(m0 - M), w1 = __expf(m1 - M);
        float w2 = __expf(m2 - M), w3 = __expf(m3 - M);
        float L = w0 * PB[4128 + j] + w1 * PB[PARTSZ + 4128 + j]
                + w2 * PB[2 * PARTSZ + 4128 + j] + w3 * PB[3 * PARTSZ + 4128 + j];
        wgt[0][j] = w0; wgt[1][j] = w1; wgt[2][j] = w2; wgt[3][j] = w3;
        inv[j] = 1.f / L;
    }
    __syncthreads();
    #pragma unroll
    for (int it = 0; it < 4; ++it) {
        int idx = it * 1024 + tid;
        int j = idx >> 7, c = idx & 127;
        float v = wgt[0][j] * PB[idx] + wgt[1][j] * PB[PARTSZ + idx]
                + wgt[2][j] * PB[2 * PARTSZ + idx] + wgt[3][j] * PB[3 * PARTSZ + idx];
        R[j * 132 + c] = v * inv[j];
    }
    __syncthreads();
    // ---- Wv projection (WvT contiguous) ----
    {
        int t = tid >> 7, col = tid & 127;
        int h = col >> 5;
        const float* rp = &R[(h * 8 + t) * 132];
        const float* wp = MW + MW_WVT + (size_t)l * 16384 + col * 128;
        float acc = qkv_b[256 + col];
        for (int c = 0; c < 128; c += 8) {
            float4 wa = *(const float4*)(wp + c);
            float4 wb = *(const float4*)(wp + c + 4);
            acc += rp[c] * wa.x + rp[c + 1] * wa.y + rp[c + 2] * wa.z + rp[c + 3] * wa.w;
            acc += rp[c + 4] * wb.x + rp[c + 5] * wb.y + rp[c + 6] * wb.z + rp[c + 7] * wb.w;
        }
        hn[t][col] = acc;
    }
    __syncthreads();
    // ---- ao projection -> tok (aoT contiguous) ----
    {
        int t = tid >> 7, col = tid & 127;
        const float* hp = hn[t];
        const float* wp = MW + MW_AOT + (size_t)l * 16384 + col * 128;
        float acc = ao_b[col];
        for (int k = 0; k < 128; k += 8) {
            float4 wa = *(const float4*)(wp + k);
            float4 wb = *(const float4*)(wp + k + 4);
            acc += hp[k] * wa.x + hp[k + 1] * wa.y + hp[k + 2] * wa.z + hp[k + 3] * wa.w;
            acc += hp[k + 4] * wb.x + hp[k + 5] * wb.y + hp[k + 6] * wb.z + hp[k + 7] * wb.w;
        }
        tok[t][col] = acc;
    }
    __syncthreads();

    // ---- rmsnorm(tok) -> hn ----
    if (tid < 512) {
        int t = tid >> 6, lane = tid & 63;
        float v0 = tok[t][lane], v1 = tok[t][lane + 64];
        float s = v0 * v0 + v1 * v1;
        #pragma unroll
        for (int off = 32; off; off >>= 1) s += __shfl_down(s, off);
        s = __shfl(s, 0);
        float r = rsqrtf(s * (1.f / 128.f) + 1e-5f);
        hn[t][lane] = v0 * r * norm_w[lane];
        hn[t][lane + 64] = v1 * r * norm_w[lane + 64];
    }
    __syncthreads();
    // ---- in_w (inT contiguous): each thread one col, 4 tokens ----
    {
        int j = tid & 511, tq = tid >> 9;
        float acc[4] = {0.f, 0.f, 0.f, 0.f};
        const float* wp = MW + MW_INT + (size_t)j * 128;
        for (int c = 0; c < 128; c += 8) {
            float4 wa = *(const float4*)(wp + c);
            float4 wb = *(const float4*)(wp + c + 4);
            float w[8] = {wa.x, wa.y, wa.z, wa.w, wb.x, wb.y, wb.z, wb.w};
            #pragma unroll
            for (int q = 0; q < 8; ++q) {
                float wq = w[q];
                #pragma unroll
                for (int k = 0; k < 4; ++k) acc[k] += hn[tq * 4 + k][c + q] * wq;
            }
        }
        if (j < 256) {
            #pragma unroll
            for (int k = 0; k < 4; ++k) uu[tq * 4 + k][j] = acc[k];
        } else {
            #pragma unroll
            for (int k = 0; k < 4; ++k) gg[tq * 4 + k][j - 256] = acc[k];
        }
    }
    __syncthreads();
    // ---- causal conv1d + silu ----
    if (tid < 256) {
        int i = tid;
        float cw0 = conv_w[i * 4 + 0], cw1 = conv_w[i * 4 + 1];
        float cw2 = conv_w[i * 4 + 2], cw3 = conv_w[i * 4 + 3];
        float cb = conv_b[i];
        float uv[TTOK];
        #pragma unroll
        for (int t = 0; t < TTOK; ++t) uv[t] = uu[t][i];
        #pragma unroll
        for (int t = 0; t < TTOK; ++t) {
            float a = cw3 * uv[t] + cb;
            if (t >= 1) a += cw2 * uv[t - 1];
            if (t >= 2) a += cw1 * uv[t - 2];
            if (t >= 3) a += cw0 * uv[t - 3];
            float sg = 1.f / (1.f + __expf(-a));
            uu[t][i] = a * sg;
        }
    }
    __syncthreads();
    // ---- x_w (xT contiguous): [8,256]@[256,40] -> ssm ----
    {
        int t = tid >> 7, j = tid & 127;
        if (j < 40) {
            float acc = 0.f;
            const float* wp = MW + MW_XT + (size_t)j * 256;
            const float* up = uu[t];
            for (int c = 0; c < 256; c += 8) {
                float4 wa = *(const float4*)(wp + c);
                float4 wb = *(const float4*)(wp + c + 4);
                acc += up[c] * wa.x + up[c + 1] * wa.y + up[c + 2] * wa.z + up[c + 3] * wa.w;
                acc += up[c + 4] * wb.x + up[c + 5] * wb.y + up[c + 6] * wb.z + up[c + 7] * wb.w;
            }
            ssm[t][j] = acc;
        }
    }
    __syncthreads();
    // ---- selective scan with fused dt projection (dtT contiguous) ----
    if (tid < 256) {
        int i = tid;
        const float4* dp = (const float4*)(MW + MW_DTT + (size_t)i * 8);
        float4 d0 = dp[0], d1 = dp[1];
        float dw[8] = {d0.x, d0.y, d0.z, d0.w, d1.x, d1.y, d1.z, d1.w};
        float dtbias = dt_b[i];
        float a[S], st[S];
        #pragma unroll
        for (int s = 0; s < S; ++s) { a[s] = -__expf(A_log[i * S + s]); st[s] = 0.f; }
        float Di = Dp[i];
        for (int t = 0; t < TTOK; ++t) {
            float d = dtbias;
            #pragma unroll
            for (int r = 0; r < 8; ++r) d += ssm[t][r] * dw[r];
            d = (d > 20.f) ? d : log1pf(__expf(d));
            float ut = uu[t][i];
            float du = d * ut;
            float y = 0.f;
            #pragma unroll
            for (int s = 0; s < S; ++s) {
                float dA = __expf(d * a[s]);
                st[s] = dA * st[s] + du * ssm[t][8 + s];
                y += st[s] * ssm[t][24 + s];
            }
            y += ut * Di;
            float g = gg[t][i];
            float sg = 1.f / (1.f + __expf(-g));
            yy[t][i] = y * g * sg;
        }
    }
    __syncthreads();
    // ---- out_w + residual (outT contiguous) ----
    {
        int t = tid >> 7, c = tid & 127;
        float acc = tok[t][c];
        const float* wp = MW + MW_OUT + (size_t)c * 256;
        const float* yp = yy[t];
        for (int i = 0; i < 256; i += 8) {
            float4 wa = *(const float4*)(wp + i);
            float4 wb = *(const float4*)(wp + i + 4);
            acc += yp[i] * wa.x + yp[i + 1] * wa.y + yp[i + 2] * wa.z + yp[i + 3] * wa.w;
            acc += yp[i + 4] * wb.x + yp[i + 5] * wb.y + yp[i + 6] * wb.z + yp[i + 7] * wb.w;
        }
        hn[t][c] = acc;
    }
    __syncthreads();
    // ---- final rmsnorm ----
    if (tid < 512) {
        int t = tid >> 6, lane = tid & 63;
        float v0 = hn[t][lane], v1 = hn[t][lane + 64];
        float s = v0 * v0 + v1 * v1;
        #pragma unroll
        for (int off = 32; off; off >>= 1) s += __shfl_down(s, off);
        s = __shfl(s, 0);
        float r = rsqrtf(s * (1.f / 128.f) + 1e-5f);
        hn[t][lane] = v0 * r * normf_w[lane];
        hn[t][lane + 64] = v1 * r * normf_w[lane + 64];
    }
    __syncthreads();
    // ---- mean over tokens -> GF ----
    if (tid < 128) {
        float s = 0.f;
        #pragma unroll
        for (int t = 0; t < TTOK; ++t) s += hn[t][tid];
        GF[(size_t)b * HDIM + tid] = s * (1.f / TTOK);
    }
}

// ================= final: per-src-bucket u8 count histogram + MFMA counts@X =================
__global__ __launch_bounds__(512) void final_count_kernel(const ushort* __restrict__ X,
    const uint* __restrict__ pairbuf, const int* __restrict__ bcount,
    float* __restrict__ PS2)
{
    __shared__ uint hist[128 * 66];     // u8 counts [graph][src/4], padded: 33 KB
    __shared__ ushort Xb[128 * 128];    // 32 KB swizzled half-tile
    int bkt = blockIdx.x, tid = threadIdx.x;
    for (int i = tid; i < 128 * 66; i += 512) hist[i] = 0u;
    __syncthreads();
    int nb = min(bcount[bkt], BCAP);
    const uint* pp = pairbuf + (size_t)bkt * BCAP;
    for (int i = tid; i < nb; i += 512) {
        uint p = pp[i];
        int g = (int)(p & 0x1FFFFu);
        int s = (int)((p >> 17) & 255);
        atomicAdd(&hist[g * 66 + (s >> 2)], 1u << ((s & 3) * 8));
    }
    if (tid < 256) {                          // self term
        int g = bkt >> 2;
        atomicAdd(&hist[g * 66 + (tid >> 2)], 1u << ((tid & 3) * 8));
    }
    int wave = tid >> 6, lane = tid & 63;
    int m16 = lane & 15, quad = lane >> 4;
    int grow = wave * 16 + m16;
    f32x4 acc[8] = {};
    for (int half = 0; half < 2; ++half) {
        __syncthreads();
        {
            const uint4* xs = (const uint4*)(X + ((size_t)bkt * 256 + half * 128) * HDIM);
            uint4* xl = (uint4*)Xb;
            for (int i = tid; i < 2048; i += 512) {
                int row = i >> 4, cc = i & 15;
                xl[row * 16 + (cc ^ (row & 15))] = xs[i];
            }
        }
        __syncthreads();
        #pragma unroll
        for (int kc = 0; kc < 4; ++kc) {
            int s0 = half * 128 + kc * 32 + quad * 8;
            uint w0 = hist[grow * 66 + (s0 >> 2)];
            uint w1 = hist[grow * 66 + (s0 >> 2) + 1];
            short8 afr;
            ((uint*)&afr)[0] = pk((float)(w0 & 255u), (float)((w0 >> 8) & 255u));
            ((uint*)&afr)[1] = pk((float)((w0 >> 16) & 255u), (float)(w0 >> 24));
            ((uint*)&afr)[2] = pk((float)(w1 & 255u), (float)((w1 >> 8) & 255u));
            ((uint*)&afr)[3] = pk((float)((w1 >> 16) & 255u), (float)(w1 >> 24));
            #pragma unroll
            for (int ct = 0; ct < 8; ++ct) {
                int n = ct * 16 + m16;
                int chi = n >> 3, clo = n & 7;
                short8 bx;
                #pragma unroll
                for (int j = 0; j < 8; ++j) {
                    int k = kc * 32 + quad * 8 + j;
                    bx[j] = (short)Xb[(k << 7) + ((chi ^ (k & 15)) << 3) + clo];
                }
                acc[ct] = __builtin_amdgcn_mfma_f32_16x16x32_bf16(afr, bx, acc[ct], 0, 0, 0);
            }
        }
    }
    float* PBo = PS2 + (size_t)bkt * 16384;
    #pragma unroll
    for (int ct = 0; ct < 8; ++ct) {
        int n = ct * 16 + m16;
        #pragma unroll
        for (int r = 0; r < 4; ++r)
            PBo[(wave * 16 + quad * 4 + r) * 128 + n] = acc[ct][r];
    }
}

// ================= final reduce + tiny matmul =================
__global__ __launch_bounds__(128) void final_mm_kernel(const float* __restrict__ PS2,
    const float* __restrict__ w_out, const float* __restrict__ b_out,
    float* __restrict__ out)
{
    __shared__ float Sm[HDIM];
    int b = blockIdx.x, tid = threadIdx.x;
    float s0 = 0.f, s1 = 0.f, s2 = 0.f, s3 = 0.f;
    const float* base = PS2 + (size_t)b * 128 + tid;
    for (int blk = 0; blk < 512; blk += 4) {
        s0 += base[(size_t)(blk + 0) * 16384];
        s1 += base[(size_t)(blk + 1) * 16384];
        s2 += base[(size_t)(blk + 2) * 16384];
        s3 += base[(size_t)(blk + 3) * 16384];
    }
    Sm[tid] = (s0 + s1) + (s2 + s3);
    __syncthreads();
    float acc = 1024.f * b_out[tid];
    for (int k = 0; k < 128; ++k) acc += Sm[k] * w_out[k * 128 + tid];
    out[(size_t)b * HDIM + tid] = acc;
}

extern "C" void kernel_launch(void* const* d_in, const int* in_sizes, int n_in,
                              void* d_out, int out_size, void* d_ws, size_t ws_size,
                              hipStream_t stream)
{
    const int N = in_sizes[0] / HDIM;      // 131072
    const int E = in_sizes[1] / 2;         // 2097152
    const int B = N >> 10;                 // 128 graphs

    const float* x_in  = (const float*)d_in[0];
    const int*   src   = (const int*)d_in[1];
    const int*   dst   = src + E;
    const float* w_in  = (const float*)d_in[5];
    const float* b_in  = (const float*)d_in[6];
    const float* gin_w = (const float*)d_in[7];
    const float* gin_b = (const float*)d_in[8];
    const float* vt    = (const float*)d_in[9];
    const float* qkv_w = (const float*)d_in[10];
    const float* qkv_b = (const float*)d_in[11];
    const float* ao_w  = (const float*)d_in[12];
    const float* ao_b  = (const float*)d_in[13];
    const float* m_in_w   = (const float*)d_in[14];
    const float* m_conv_w = (const float*)d_in[15];
    const float* m_conv_b = (const float*)d_in[16];
    const float* m_x_w    = (const float*)d_in[17];
    const float* m_dt_w   = (const float*)d_in[18];
    const float* m_dt_b   = (const float*)d_in[19];
    const float* m_A_log  = (const float*)d_in[20];
    const float* m_D      = (const float*)d_in[21];
    const float* m_out_w  = (const float*)d_in[22];
    const float* m_norm_w = (const float*)d_in[23];
    const float* m_normf_w= (const float*)d_in[24];
    const float* w_out = (const float*)d_in[25];
    const float* b_out = (const float*)d_in[26];
    float* out = (float*)d_out;

    float* GF  = (float*)d_ws;                        // B*128
    float* P   = GF + (size_t)B * HDIM;               // 2*4*8*128
    float* PART= P + 2 * 4 * TTOK * HDIM;             // B*4*PARTSZ
    int* bcursor  = (int*)(PART + (size_t)B * 4 * PARTSZ); // 512 (dst bins)
    int* bcursor2 = bcursor + NBUCK;                  // 512 (src bins) — zeroed together
    int* count    = bcursor2 + NBUCK;                 // N
    int* starts   = count + N;                        // N+1 (padded to N+8)
    int* ssrc     = starts + N + 8;                   // E
    float* MW     = (float*)(ssrc + E);               // transposed mamba weights
    uint* pairbuf = (uint*)(MW + MW_TOT);             // NBUCK*BCAP uints (dst bins, then src bins)
    float* PS2    = (float*)(pairbuf + (size_t)NBUCK * BCAP); // 512*16384 f32 partials
    ushort* AGG = (ushort*)PS2;                       // N*128 bf16 — ALIASES PS2 (AGG dead before final)
    ushort* XB0 = (ushort*)(PS2 + (size_t)NBUCK * 128 * 128); // N*128 bf16
    ushort* XB1 = XB0 + (size_t)N * HDIM;             // N*128 bf16

    const int NBB = (E + EPB - 1) / EPB;   // 512

    // ---- dst-bin + convert in one launch ----
    hipMemsetAsync(bcursor, 0, 2 * NBUCK * sizeof(int), stream);
    bin_conv_kernel<<<NBB + 2048, 256, 0, stream>>>(src, dst, bcursor, pairbuf, E,
                                                    x_in, XB0, N * 32);
    bucket_sort_kernel<<<NBUCK, 256, 0, stream>>>(pairbuf, bcursor, ssrc, starts, count, N);
    // ---- attn prep + weight transposes + src-bin (pairbuf reused post-sort) ----
    prep_binsrc_kernel<<<690 + NBB, 256, 0, stream>>>(vt, qkv_w, qkv_b, P,
                                                      ao_w, m_in_w, m_x_w, m_dt_w, m_out_w, MW,
                                                      src, dst, bcursor2, pairbuf, E);

    // ---- input GIN: gather + MFMA linear ----
    gather_kernel<<<N / 16, 256, 0, stream>>>(XB0, ssrc, starts, count, AGG);
    lin128_mfma_kernel<<<N / 128, 256, 0, stream>>>(AGG, w_in, b_in, nullptr, XB1);

    ushort* Xcur = XB1;
    ushort* Xnext = XB0;
    const int nAG = B * 4 + N / 16;   // 512 attn + 8192 gather = 8704 = 17*512
    for (int l = 0; l < 2; ++l) {
        attn_gather_kernel<<<nAG, 256, 0, stream>>>(Xcur, P + (size_t)l * 4 * TTOK * HDIM,
                                                    PART, ssrc, starts, count, AGG);
        mamba_kernel<<<B, 1024, 0, stream>>>(PART,
                                             qkv_b + (size_t)l * 384,
                                             ao_b + (size_t)l * 128,
                                             MW, l,
                                             m_conv_w, m_conv_b, m_dt_b, m_A_log, m_D,
                                             m_norm_w, m_normf_w, GF);
        lin128_mfma_kernel<<<N / 128, 256, 0, stream>>>(AGG, gin_w + (size_t)l * 128 * 128,
                                                        gin_b + (size_t)l * 128, GF, Xnext);
        ushort* t = Xcur; Xcur = Xnext; Xnext = t;
    }

    // ---- final GIN + segment_sum: counts-MFMA partials + tiny matmul (overwrites AGG) ----
    final_count_kernel<<<NBUCK, 512, 0, stream>>>(Xcur, pairbuf, bcursor2, PS2);
    final_mm_kernel<<<B, 128, 0, stream>>>(PS2, w_out, b_out, out);

    (void)n_in; (void)out_size; (void)ws_size;
}

// Round 7
// 823.296 us; speedup vs baseline: 1.1685x; 1.1685x over previous
//
#include <hip/hip_runtime.h>

#define HDIM 128
#define TTOK 8
#define NPG 1024
#define NBUCK 512
#define BSHIFT 8
#define BCAP 5120
#define EPB 4096
#define PARTSZ 4160   // per (graph,part): 32*128 O + 32 m + 32 l

typedef unsigned short ushort;
typedef unsigned int uint;
typedef __attribute__((ext_vector_type(8))) short short8;
typedef __attribute__((ext_vector_type(4))) float f32x4;

__device__ __forceinline__ ushort f2bf(float f) {
    unsigned int x = __float_as_uint(f);
    return (ushort)((x + 0x7FFFu + ((x >> 16) & 1u)) >> 16);
}
__device__ __forceinline__ float blo(uint u) { return __uint_as_float(u << 16); }
__device__ __forceinline__ float bhi(uint u) { return __uint_as_float(u & 0xFFFF0000u); }
__device__ __forceinline__ uint pk(float a, float b) {
    return (uint)f2bf(a) | ((uint)f2bf(b) << 16);
}

// ================= bin body (mode 0: key=dst pay=src; mode 1: key=src pay=graph(dst)) =================
__device__ __forceinline__ void bin_body(const int* __restrict__ src,
    const int* __restrict__ dst, int mode, int* __restrict__ bcursor,
    uint* __restrict__ pairbuf, int E, int e0, int tid,
    int* lcnt, int* lbase)
{
    for (int i = tid; i < NBUCK; i += 256) lcnt[i] = 0;
    __syncthreads();
    uint pkd[16];
    int bk[16], rk[16];
    #pragma unroll
    for (int i = 0; i < 16; ++i) {
        int e = e0 + i * 256 + tid;
        int s = (e < E) ? src[e] : 0;
        int d = (e < E) ? dst[e] : 0;
        int key = mode ? s : d;
        uint pay = mode ? (uint)(d >> 10) : (uint)s;
        if (e >= E) key = -1;
        int b = key >> BSHIFT;
        bk[i] = b;
        pkd[i] = ((uint)(key & 255) << 17) | pay;
        rk[i] = (key >= 0) ? atomicAdd(&lcnt[b], 1) : 0;
    }
    __syncthreads();
    for (int i = tid; i < NBUCK; i += 256) {
        int c = lcnt[i];
        lbase[i] = c ? atomicAdd(&bcursor[i], c) : 0;
    }
    __syncthreads();
    #pragma unroll
    for (int i = 0; i < 16; ++i) {
        if (bk[i] >= 0) {
            int slot = lbase[bk[i]] + rk[i];
            if (slot < BCAP) pairbuf[(size_t)bk[i] * BCAP + slot] = pkd[i];
        }
    }
}

// ================= dst-bin + f32->bf16 convert, one launch =================
__global__ __launch_bounds__(256) void bin_conv_kernel(const int* __restrict__ src,
    const int* __restrict__ dst, int* __restrict__ bcursor, uint* __restrict__ pairbuf,
    int E, const float* __restrict__ xin, ushort* __restrict__ outb, int n4)
{
    __shared__ int lcnt[NBUCK];
    __shared__ int lbase[NBUCK];
    int tid = threadIdx.x;
    int b = blockIdx.x;
    if (b < NBUCK) {
        bin_body(src, dst, 0, bcursor, pairbuf, E, b * EPB, tid, lcnt, lbase);
    } else {
        for (int i = (b - NBUCK) * 256 + tid; i < n4; i += 2048 * 256) {
            float4 v = ((const float4*)xin)[i];
            uint2 o;
            o.x = pk(v.x, v.y); o.y = pk(v.z, v.w);
            ((uint2*)outb)[i] = o;
        }
    }
}

// ================= Pass B (dst-sort): one block per bucket; self-scans bucket counts =================
__global__ __launch_bounds__(256) void bucket_sort_kernel(const uint* __restrict__ pairbuf,
    const int* __restrict__ bcount,
    int* __restrict__ ssrc, int* __restrict__ starts, int* __restrict__ countn, int N)
{
    __shared__ int sc[NBUCK];
    __shared__ int lcount[256];
    __shared__ int lcur[256];
    __shared__ int lss[BCAP];   // 20 KB
    int b = blockIdx.x;
    int tid = threadIdx.x;
    sc[tid] = min(bcount[tid], BCAP);
    sc[tid + 256] = min(bcount[tid + 256], BCAP);
    lcount[tid] = 0;
    __syncthreads();
    for (int off = 1; off < NBUCK; off <<= 1) {
        int a0 = (tid >= off) ? sc[tid - off] : 0;
        int a1 = (tid + 256 >= off) ? sc[tid + 256 - off] : 0;
        __syncthreads();
        sc[tid] += a0; sc[tid + 256] += a1;
        __syncthreads();
    }
    int nb = min(bcount[b], BCAP);
    int base = sc[b] - nb;
    const uint* pp = pairbuf + (size_t)b * BCAP;
    for (int i = tid; i < nb; i += 256)
        atomicAdd(&lcount[(pp[i] >> 17) & 255], 1);
    __syncthreads();
    int v = lcount[tid];
    lcur[tid] = v;
    __syncthreads();
    for (int off = 1; off < 256; off <<= 1) {
        int t = (tid >= off) ? lcur[tid - off] : 0;
        __syncthreads();
        lcur[tid] += t;
        __syncthreads();
    }
    int excl = lcur[tid] - v;
    int node = b * 256 + tid;
    starts[node] = base + excl;
    countn[node] = v;
    __syncthreads();
    lcur[tid] = excl;
    __syncthreads();
    for (int i = tid; i < nb; i += 256) {
        uint p = pp[i];
        int pos = atomicAdd(&lcur[(p >> 17) & 255], 1);
        lss[pos] = (int)(p & 0x1FFFFu);
    }
    __syncthreads();
    for (int i = tid; i < nb; i += 256) ssrc[base + i] = lss[i];
    if (b == NBUCK - 1 && tid == 0) starts[N] = base + nb;
}

// ================= gather body: 16 nodes, 16 lanes each, 8-deep ILP =================
__device__ __forceinline__ void gather16_body(const ushort* __restrict__ XS,
    const int* __restrict__ ssrc, const int* __restrict__ starts,
    const int* __restrict__ count, ushort* __restrict__ AGG, int nbase, int tid)
{
    int g = tid >> 4, lane = tid & 15;
    int node = nbase + g;
    uint4 sv = *((const uint4*)(XS + (size_t)node * HDIM) + lane);
    float a0 = blo(sv.x), a1 = bhi(sv.x), a2 = blo(sv.y), a3 = bhi(sv.y);
    float a4 = blo(sv.z), a5 = bhi(sv.z), a6 = blo(sv.w), a7 = bhi(sv.w);
    int s0 = starts[node], cn = count[node];
    for (int j0 = 0; j0 < cn; j0 += 16) {
        int myid = (j0 + lane < cn) ? ssrc[s0 + j0 + lane] : 0;
        int m = min(16, cn - j0);
        int j = 0;
        for (; j + 7 < m; j += 8) {
            uint4 u[8];
            #pragma unroll
            for (int q = 0; q < 8; ++q) {
                int sidx = __shfl(myid, j + q, 16);
                u[q] = *((const uint4*)(XS + (size_t)sidx * HDIM) + lane);
            }
            #pragma unroll
            for (int q = 0; q < 8; ++q) {
                a0 += blo(u[q].x); a1 += bhi(u[q].x);
                a2 += blo(u[q].y); a3 += bhi(u[q].y);
                a4 += blo(u[q].z); a5 += bhi(u[q].z);
                a6 += blo(u[q].w); a7 += bhi(u[q].w);
            }
        }
        for (; j + 3 < m; j += 4) {
            uint4 u[4];
            #pragma unroll
            for (int q = 0; q < 4; ++q) {
                int sidx = __shfl(myid, j + q, 16);
                u[q] = *((const uint4*)(XS + (size_t)sidx * HDIM) + lane);
            }
            #pragma unroll
            for (int q = 0; q < 4; ++q) {
                a0 += blo(u[q].x); a1 += bhi(u[q].x);
                a2 += blo(u[q].y); a3 += bhi(u[q].y);
                a4 += blo(u[q].z); a5 += bhi(u[q].z);
                a6 += blo(u[q].w); a7 += bhi(u[q].w);
            }
        }
        for (; j < m; ++j) {
            int sidx = __shfl(myid, j, 16);
            uint4 ua = *((const uint4*)(XS + (size_t)sidx * HDIM) + lane);
            a0 += blo(ua.x); a1 += bhi(ua.x);
            a2 += blo(ua.y); a3 += bhi(ua.y);
            a4 += blo(ua.z); a5 += bhi(ua.z);
            a6 += blo(ua.w); a7 += bhi(ua.w);
        }
    }
    uint4 o;
    o.x = pk(a0, a1); o.y = pk(a2, a3); o.z = pk(a4, a5); o.w = pk(a6, a7);
    *((uint4*)(AGG + (size_t)node * HDIM) + lane) = o;
}

// ================= input-GIN gather ∥ attn-prep ∥ src-bin (one dispatch) =================
// blocks 0-1: attn P prep (long; scheduled first); [2, 2+8192): gather; [8194, 8706): src-bin.
__global__ __launch_bounds__(256) void gather_prep_kernel(const ushort* __restrict__ XS,
    const int* __restrict__ ssrc, const int* __restrict__ starts,
    const int* __restrict__ count, ushort* __restrict__ AGG,
    const float* __restrict__ vt, const float* __restrict__ qkv_w,
    const float* __restrict__ qkv_b, float* __restrict__ P,
    const int* __restrict__ src, const int* __restrict__ dst,
    int* __restrict__ bcursor2, uint* __restrict__ pairbuf, int E)
{
    __shared__ float vtl[TTOK][HDIM];
    __shared__ float q[TTOK][HDIM];
    __shared__ int lcnt[NBUCK];
    __shared__ int lbase[NBUCK];
    int b = blockIdx.x, tid = threadIdx.x;
    if (b < 2) {
        int l = b;
        const float* vtp = vt + (size_t)l * TTOK * HDIM;
        const float* qw = qkv_w + (size_t)l * 128 * 384;
        const float* qb = qkv_b + (size_t)l * 384;
        float* Pp = P + (size_t)l * 4 * TTOK * HDIM;
        for (int i = tid; i < TTOK * HDIM; i += 256) vtl[i >> 7][i & 127] = vtp[i];
        __syncthreads();
        for (int i = tid; i < TTOK * HDIM; i += 256) {
            int t = i >> 7, j = i & 127;
            float acc = qb[j];
            for (int c = 0; c < 128; ++c) acc += vtl[t][c] * qw[c * 384 + j];
            q[t][j] = acc;
        }
        __syncthreads();
        const float scale = 0.17677669529663687f; // 1/sqrt(32)
        for (int i = tid; i < 4 * TTOK * HDIM; i += 256) {
            int h = i >> 10, t = (i >> 7) & 7, cc = i & 127;
            float acc = 0.f;
            for (int d = 0; d < 32; ++d)
                acc += qw[cc * 384 + 128 + h * 32 + d] * q[t][h * 32 + d];
            Pp[i] = acc * scale;
        }
    } else if (b < 8194) {
        gather16_body(XS, ssrc, starts, count, AGG, (b - 2) * 16, tid);
    } else {
        bin_body(src, dst, 1, bcursor2, pairbuf, E, (b - 8194) * EPB, tid, lcnt, lbase);
    }
}

// ================= attention body v3: 64-node tiles, ~25.2 KB LDS (St/P union) =================
__device__ __forceinline__ void attn_body(const ushort* __restrict__ X,
    const float* __restrict__ P, float* __restrict__ PART, int bp, int tid)
{
    __shared__ ushort Xl[64 * 128];    // 16 KB swizzled X tile (64 nodes)
    __shared__ float  StU[32 * 68];    // 8.5 KB union: prologue-P bf16 / scores f32 / exp-P bf16
    __shared__ float lm[32], ll[32], lalpha[32];
    ushort* PlU = (ushort*)StU;
    int b = bp >> 2, part = bp & 3;
    int wave = tid >> 6, lane = tid & 63;
    int m16 = lane & 15, quad = lane >> 4;

    for (int i = tid; i < 2048; i += 256) {
        float2 v = *(const float2*)(P + (size_t)i * 2);
        ((uint*)PlU)[i] = pk(v.x, v.y);
    }
    if (tid < 32) { lm[tid] = -1e30f; ll[tid] = 0.f; }
    __syncthreads();
    short8 aP[2][4];
    #pragma unroll
    for (int mt = 0; mt < 2; ++mt)
        #pragma unroll
        for (int kc = 0; kc < 4; ++kc)
            aP[mt][kc] = *(const short8*)&PlU[(mt * 16 + m16) * 128 + (kc * 4 + quad) * 8];
    __syncthreads();

    f32x4 oacc[2][2] = {};
    const uint4* xsg = (const uint4*)(X + (size_t)b * NPG * HDIM);

    for (int tt = 0; tt < 4; ++tt) {
        {
            const uint4* xs = xsg + (part * 4 + tt) * 1024;
            uint4* xl = (uint4*)Xl;
            for (int i = tid; i < 1024; i += 256) {
                int row = i >> 4, cc = i & 15;
                xl[row * 16 + (cc ^ (row & 15))] = xs[i];
            }
        }
        __syncthreads();
        {
            f32x4 sacc[2] = {};
            #pragma unroll
            for (int kc = 0; kc < 4; ++kc) {
                int node = wave * 16 + m16;
                short8 bx = *(const short8*)&Xl[node * 128 + (((kc * 4 + quad) ^ m16) << 3)];
                sacc[0] = __builtin_amdgcn_mfma_f32_16x16x32_bf16(aP[0][kc], bx, sacc[0], 0, 0, 0);
                sacc[1] = __builtin_amdgcn_mfma_f32_16x16x32_bf16(aP[1][kc], bx, sacc[1], 0, 0, 0);
            }
            #pragma unroll
            for (int mt = 0; mt < 2; ++mt)
                #pragma unroll
                for (int r = 0; r < 4; ++r)
                    StU[(mt * 16 + quad * 4 + r) * 68 + wave * 16 + m16] = sacc[mt][r];
        }
        __syncthreads();
        {
            int j = tid >> 3, g = tid & 7;
            const float* rowp = &StU[j * 68 + g * 8];
            float4 v0 = *(const float4*)(rowp);
            float4 v1 = *(const float4*)(rowp + 4);
            float mx = fmaxf(fmaxf(fmaxf(v0.x, v0.y), fmaxf(v0.z, v0.w)),
                             fmaxf(fmaxf(v1.x, v1.y), fmaxf(v1.z, v1.w)));
            mx = fmaxf(mx, __shfl_down(mx, 4, 8));
            mx = fmaxf(mx, __shfl_down(mx, 2, 8));
            mx = fmaxf(mx, __shfl_down(mx, 1, 8));
            mx = __shfl(mx, 0, 8);
            float mold = lm[j];
            float Mn = fmaxf(mold, mx);
            float alpha = __expf(mold - Mn);
            float p0 = __expf(v0.x - Mn), p1 = __expf(v0.y - Mn);
            float p2 = __expf(v0.z - Mn), p3 = __expf(v0.w - Mn);
            float p4 = __expf(v1.x - Mn), p5 = __expf(v1.y - Mn);
            float p6 = __expf(v1.z - Mn), p7 = __expf(v1.w - Mn);
            float s = ((p0 + p1) + (p2 + p3)) + ((p4 + p5) + (p6 + p7));
            s += __shfl_down(s, 4, 8);
            s += __shfl_down(s, 2, 8);
            s += __shfl_down(s, 1, 8);
            if (g == 0) {
                ll[j] = ll[j] * alpha + s;
                lm[j] = Mn;
                lalpha[j] = alpha;
            }
            __syncthreads();   // all St reads complete before exp-P overwrites the union
            uint4 u0;
            u0.x = pk(p0, p1); u0.y = pk(p2, p3); u0.z = pk(p4, p5); u0.w = pk(p6, p7);
            ((uint4*)PlU)[j * 8 + (g ^ (j & 7))] = u0;   // exp-P [32][64], chunk-swizzled
        }
        __syncthreads();
        {
            #pragma unroll
            for (int mt = 0; mt < 2; ++mt)
                #pragma unroll
                for (int r = 0; r < 4; ++r) {
                    float a = lalpha[mt * 16 + quad * 4 + r];
                    oacc[mt][0][r] *= a;
                    oacc[mt][1][r] *= a;
                }
            #pragma unroll
            for (int kc = 0; kc < 2; ++kc) {
                short8 ap2[2], bx[2];
                #pragma unroll
                for (int mt = 0; mt < 2; ++mt)
                    ap2[mt] = *(const short8*)&PlU[(mt * 16 + m16) * 64
                                                   + (((kc * 4 + quad) ^ (m16 & 7)) << 3)];
                #pragma unroll
                for (int ntl = 0; ntl < 2; ++ntl) {
                    int cf = (2 * wave + ntl) * 16 + m16;
                    int chi = cf >> 3, clo = cf & 7;
                    short8 v;
                    #pragma unroll
                    for (int jj = 0; jj < 8; ++jj) {
                        int row = kc * 32 + quad * 8 + jj;
                        v[jj] = (short)Xl[(row << 7) + ((chi ^ (row & 15)) << 3) + clo];
                    }
                    bx[ntl] = v;
                }
                #pragma unroll
                for (int mt = 0; mt < 2; ++mt)
                    #pragma unroll
                    for (int ntl = 0; ntl < 2; ++ntl)
                        oacc[mt][ntl] = __builtin_amdgcn_mfma_f32_16x16x32_bf16(
                            ap2[mt], bx[ntl], oacc[mt][ntl], 0, 0, 0);
            }
        }
        __syncthreads();
    }
    float* PB = PART + ((size_t)b * 4 + part) * PARTSZ;
    #pragma unroll
    for (int mt = 0; mt < 2; ++mt)
        #pragma unroll
        for (int r = 0; r < 4; ++r) {
            int j = mt * 16 + quad * 4 + r;
            PB[j * 128 + (2 * wave + 0) * 16 + m16] = oacc[mt][0][r];
            PB[j * 128 + (2 * wave + 1) * 16 + m16] = oacc[mt][1][r];
        }
    if (tid < 32) { PB[4096 + tid] = lm[tid]; PB[4128 + tid] = ll[tid]; }
}

// ================= combined attention ∥ gather (independent work, one dispatch) =================
__global__ __launch_bounds__(256) void attn_gather_kernel(const ushort* __restrict__ X,
    const float* __restrict__ P, float* __restrict__ PART,
    const int* __restrict__ ssrc, const int* __restrict__ starts,
    const int* __restrict__ count, ushort* __restrict__ AGG)
{
    int bp = blockIdx.x;
    if (bp % 17 == 0) {
        attn_body(X, P, PART, bp / 17, threadIdx.x);
    } else {
        int gidx = bp - bp / 17 - 1;
        gather16_body(X, ssrc, starts, count, AGG, gidx * 16, threadIdx.x);
    }
}

// ================= MFMA linear (bf16 in/out): XD = XS @ W + b [+ GF[row>>10]] =================
__global__ __launch_bounds__(256) void lin128_mfma_kernel(const ushort* __restrict__ XS,
    const float* __restrict__ W, const float* __restrict__ bias,
    const float* __restrict__ GF, ushort* __restrict__ XD)
{
    __shared__ ushort Xl[128 * 128];
    __shared__ ushort Wl[128 * 128];
    int tid = threadIdx.x;
    size_t r0 = (size_t)blockIdx.x * 128;
    {
        const uint4* xs = (const uint4*)(XS + r0 * HDIM);
        uint4* xl = (uint4*)Xl;
        for (int i = tid; i < 2048; i += 256) {
            int row = i >> 4, cc = i & 15;
            xl[row * 16 + (cc ^ (row & 15))] = xs[i];
        }
    }
    {
        uint4* wl = (uint4*)Wl;
        for (int i = tid; i < 2048; i += 256) {
            int n = i & 127, c = i >> 7;
            const float* wp = W + (size_t)(c * 8) * 128 + n;
            float w0 = wp[0], w1 = wp[128], w2 = wp[256], w3 = wp[384];
            float w4 = wp[512], w5 = wp[640], w6 = wp[768], w7 = wp[896];
            uint4 u;
            u.x = pk(w0, w1); u.y = pk(w2, w3); u.z = pk(w4, w5); u.w = pk(w6, w7);
            wl[n * 16 + (c ^ (n & 15))] = u;
        }
    }
    __syncthreads();
    int wave = tid >> 6;
    int lane = tid & 63;
    int m16 = lane & 15, quad = lane >> 4;
    const short8* Xf = (const short8*)Xl;
    const short8* Wf = (const short8*)Wl;
    short8 afr[2][4];
    #pragma unroll
    for (int rt = 0; rt < 2; ++rt)
        #pragma unroll
        for (int kc = 0; kc < 4; ++kc)
            afr[rt][kc] = Xf[(wave * 32 + rt * 16 + m16) * 16 + ((kc * 4 + quad) ^ m16)];
    int graph = (int)(r0 >> 10);
    #pragma unroll
    for (int ct = 0; ct < 8; ++ct) {
        int col = ct * 16 + m16;
        short8 bfr[4];
        #pragma unroll
        for (int kc = 0; kc < 4; ++kc)
            bfr[kc] = Wf[col * 16 + ((kc * 4 + quad) ^ m16)];
        f32x4 acc0 = {0.f, 0.f, 0.f, 0.f};
        f32x4 acc1 = {0.f, 0.f, 0.f, 0.f};
        #pragma unroll
        for (int kc = 0; kc < 4; ++kc) {
            acc0 = __builtin_amdgcn_mfma_f32_16x16x32_bf16(afr[0][kc], bfr[kc], acc0, 0, 0, 0);
            acc1 = __builtin_amdgcn_mfma_f32_16x16x32_bf16(afr[1][kc], bfr[kc], acc1, 0, 0, 0);
        }
        float add = bias[col] + (GF ? GF[(size_t)graph * HDIM + col] : 0.f);
        #pragma unroll
        for (int r = 0; r < 4; ++r) {
            XD[(r0 + wave * 32 + quad * 4 + r) * HDIM + col] = f2bf(acc0[r] + add);
            XD[(r0 + wave * 32 + 16 + quad * 4 + r) * HDIM + col] = f2bf(acc1[r] + add);
        }
    }
}

// ================= mamba (R5 layout: strided-per-thread = wave-coalesced weights) =================
__global__ __launch_bounds__(1024) void mamba_kernel(const float* __restrict__ PART,
    const float* __restrict__ qkv_w, const float* __restrict__ qkv_b,
    const float* __restrict__ ao_w, const float* __restrict__ ao_b,
    const float* __restrict__ in_w, const float* __restrict__ conv_w,
    const float* __restrict__ conv_b, const float* __restrict__ x_w,
    const float* __restrict__ dt_w, const float* __restrict__ dt_b,
    const float* __restrict__ A_log, const float* __restrict__ Dp,
    const float* __restrict__ out_w, const float* __restrict__ norm_w,
    const float* __restrict__ normf_w, float* __restrict__ GF)
{
    constexpr int I = 256, S = 16;
    __shared__ float R[32 * 132];
    __shared__ float wgt[4][32];
    __shared__ float inv[32];
    __shared__ float tok[TTOK][HDIM];
    __shared__ float hn[TTOK][HDIM];
    __shared__ float uu[TTOK][I];
    __shared__ float gg[TTOK][I];
    __shared__ float ssm[TTOK][40];
    __shared__ float yy[TTOK][I];
    int b = blockIdx.x, tid = threadIdx.x;

    const float* PB = PART + (size_t)b * 4 * PARTSZ;
    if (tid < 32) {
        int j = tid;
        float m0 = PB[4096 + j], m1 = PB[PARTSZ + 4096 + j];
        float m2 = PB[2 * PARTSZ + 4096 + j], m3 = PB[3 * PARTSZ + 4096 + j];
        float M = fmaxf(fmaxf(m0, m1), fmaxf(m2, m3));
        float w0 = __expf(m0 - M), w1 = __expf(m1 - M);
        float w2 = __expf(m2 - M), w3 = __expf(m3 - M);
        float L = w0 * PB[4128 + j] + w1 * PB[PARTSZ + 4128 + j]
                + w2 * PB[2 * PARTSZ + 4128 + j] + w3 * PB[3 * PARTSZ + 4128 + j];
        wgt[0][j] = w0; wgt[1][j] = w1; wgt[2][j] = w2; wgt[3][j] = w3;
        inv[j] = 1.f / L;
    }
    __syncthreads();
    #pragma unroll
    for (int it = 0; it < 4; ++it) {
        int idx = it * 1024 + tid;
        int j = idx >> 7, c = idx & 127;
        float v = wgt[0][j] * PB[idx] + wgt[1][j] * PB[PARTSZ + idx]
                + wgt[2][j] * PB[2 * PARTSZ + idx] + wgt[3][j] * PB[3 * PARTSZ + idx];
        R[j * 132 + c] = v * inv[j];
    }
    __syncthreads();
    {
        int t = tid >> 7, col = tid & 127;
        int h = col >> 5;
        const float* rp = &R[(h * 8 + t) * 132];
        const float* wp = qkv_w + 256 + col;
        float acc = qkv_b[256 + col];
        for (int c = 0; c < 128; c += 8) {
            float w[8];
            #pragma unroll
            for (int q = 0; q < 8; ++q) w[q] = wp[(size_t)(c + q) * 384];
            #pragma unroll
            for (int q = 0; q < 8; ++q) acc += rp[c + q] * w[q];
        }
        hn[t][col] = acc;
    }
    __syncthreads();
    {
        int t = tid >> 7, col = tid & 127;
        const float* hp = hn[t];
        const float* wp = ao_w + col;
        float acc = ao_b[col];
        for (int k = 0; k < 128; k += 8) {
            float w[8];
            #pragma unroll
            for (int q = 0; q < 8; ++q) w[q] = wp[(size_t)(k + q) * 128];
            #pragma unroll
            for (int q = 0; q < 8; ++q) acc += hp[k + q] * w[q];
        }
        tok[t][col] = acc;
    }
    __syncthreads();

    if (tid < 512) {
        int t = tid >> 6, lane = tid & 63;
        float v0 = tok[t][lane], v1 = tok[t][lane + 64];
        float s = v0 * v0 + v1 * v1;
        #pragma unroll
        for (int off = 32; off; off >>= 1) s += __shfl_down(s, off);
        s = __shfl(s, 0);
        float r = rsqrtf(s * (1.f / 128.f) + 1e-5f);
        hn[t][lane] = v0 * r * norm_w[lane];
        hn[t][lane + 64] = v1 * r * norm_w[lane + 64];
    }
    __syncthreads();
    {
        int j = tid & 511, tq = tid >> 9;
        float acc[4] = {0.f, 0.f, 0.f, 0.f};
        const float* wp = in_w + j;
        for (int c = 0; c < 128; c += 8) {
            float w[8];
            #pragma unroll
            for (int q = 0; q < 8; ++q) w[q] = wp[(size_t)(c + q) * 512];
            #pragma unroll
            for (int q = 0; q < 8; ++q) {
                float wq = w[q];
                #pragma unroll
                for (int k = 0; k < 4; ++k) acc[k] += hn[tq * 4 + k][c + q] * wq;
            }
        }
        if (j < 256) {
            #pragma unroll
            for (int k = 0; k < 4; ++k) uu[tq * 4 + k][j] = acc[k];
        } else {
            #pragma unroll
            for (int k = 0; k < 4; ++k) gg[tq * 4 + k][j - 256] = acc[k];
        }
    }
    __syncthreads();
    if (tid < 256) {
        int i = tid;
        float cw0 = conv_w[i * 4 + 0], cw1 = conv_w[i * 4 + 1];
        float cw2 = conv_w[i * 4 + 2], cw3 = conv_w[i * 4 + 3];
        float cb = conv_b[i];
        float uv[TTOK];
        #pragma unroll
        for (int t = 0; t < TTOK; ++t) uv[t] = uu[t][i];
        #pragma unroll
        for (int t = 0; t < TTOK; ++t) {
            float a = cw3 * uv[t] + cb;
            if (t >= 1) a += cw2 * uv[t - 1];
            if (t >= 2) a += cw1 * uv[t - 2];
            if (t >= 3) a += cw0 * uv[t - 3];
            float sg = 1.f / (1.f + __expf(-a));
            uu[t][i] = a * sg;
        }
    }
    __syncthreads();
    {
        int t = tid >> 7, j = tid & 127;
        if (j < 40) {
            float acc = 0.f;
            const float* wp = x_w + j;
            const float* up = uu[t];
            for (int c = 0; c < 256; c += 8) {
                float w[8];
                #pragma unroll
                for (int q = 0; q < 8; ++q) w[q] = wp[(size_t)(c + q) * 40];
                #pragma unroll
                for (int q = 0; q < 8; ++q) acc += up[c + q] * w[q];
            }
            ssm[t][j] = acc;
        }
    }
    __syncthreads();
    if (tid < 256) {
        int i = tid;
        float dw[8];
        #pragma unroll
        for (int r = 0; r < 8; ++r) dw[r] = dt_w[r * 256 + i];
        float dtbias = dt_b[i];
        float a[S], st[S];
        #pragma unroll
        for (int s = 0; s < S; ++s) { a[s] = -__expf(A_log[i * S + s]); st[s] = 0.f; }
        float Di = Dp[i];
        for (int t = 0; t < TTOK; ++t) {
            float d = dtbias;
            #pragma unroll
            for (int r = 0; r < 8; ++r) d += ssm[t][r] * dw[r];
            d = (d > 20.f) ? d : log1pf(__expf(d));
            float ut = uu[t][i];
            float du = d * ut;
            float y = 0.f;
            #pragma unroll
            for (int s = 0; s < S; ++s) {
                float dA = __expf(d * a[s]);
                st[s] = dA * st[s] + du * ssm[t][8 + s];
                y += st[s] * ssm[t][24 + s];
            }
            y += ut * Di;
            float g = gg[t][i];
            float sg = 1.f / (1.f + __expf(-g));
            yy[t][i] = y * g * sg;
        }
    }
    __syncthreads();
    {
        int t = tid >> 7, c = tid & 127;
        float acc = tok[t][c];
        const float* wp = out_w + c;
        const float* yp = yy[t];
        for (int i = 0; i < 256; i += 8) {
            float w[8];
            #pragma unroll
            for (int q = 0; q < 8; ++q) w[q] = wp[(size_t)(i + q) * 128];
            #pragma unroll
            for (int q = 0; q < 8; ++q) acc += yp[i + q] * w[q];
        }
        hn[t][c] = acc;
    }
    __syncthreads();
    if (tid < 512) {
        int t = tid >> 6, lane = tid & 63;
        float v0 = hn[t][lane], v1 = hn[t][lane + 64];
        float s = v0 * v0 + v1 * v1;
        #pragma unroll
        for (int off = 32; off; off >>= 1) s += __shfl_down(s, off);
        s = __shfl(s, 0);
        float r = rsqrtf(s * (1.f / 128.f) + 1e-5f);
        hn[t][lane] = v0 * r * normf_w[lane];
        hn[t][lane + 64] = v1 * r * normf_w[lane + 64];
    }
    __syncthreads();
    if (tid < 128) {
        float s = 0.f;
        #pragma unroll
        for (int t = 0; t < TTOK; ++t) s += hn[t][tid];
        GF[(size_t)b * HDIM + tid] = s * (1.f / TTOK);
    }
}

// ================= final: per-src-bucket u8 count histogram + MFMA counts@X =================
__global__ __launch_bounds__(512) void final_count_kernel(const ushort* __restrict__ X,
    const uint* __restrict__ pairbuf, const int* __restrict__ bcount,
    float* __restrict__ PS2)
{
    __shared__ uint hist[128 * 66];     // u8 counts [graph][src/4], padded: 33 KB
    __shared__ ushort Xb[128 * 128];    // 32 KB swizzled half-tile
    int bkt = blockIdx.x, tid = threadIdx.x;
    for (int i = tid; i < 128 * 66; i += 512) hist[i] = 0u;
    __syncthreads();
    int nb = min(bcount[bkt], BCAP);
    const uint* pp = pairbuf + (size_t)bkt * BCAP;
    for (int i = tid; i < nb; i += 512) {
        uint p = pp[i];
        int g = (int)(p & 0x1FFFFu);
        int s = (int)((p >> 17) & 255);
        atomicAdd(&hist[g * 66 + (s >> 2)], 1u << ((s & 3) * 8));
    }
    if (tid < 256) {                          // self term
        int g = bkt >> 2;
        atomicAdd(&hist[g * 66 + (tid >> 2)], 1u << ((tid & 3) * 8));
    }
    int wave = tid >> 6, lane = tid & 63;
    int m16 = lane & 15, quad = lane >> 4;
    int grow = wave * 16 + m16;
    f32x4 acc[8] = {};
    for (int half = 0; half < 2; ++half) {
        __syncthreads();
        {
            const uint4* xs = (const uint4*)(X + ((size_t)bkt * 256 + half * 128) * HDIM);
            uint4* xl = (uint4*)Xb;
            for (int i = tid; i < 2048; i += 512) {
                int row = i >> 4, cc = i & 15;
                xl[row * 16 + (cc ^ (row & 15))] = xs[i];
            }
        }
        __syncthreads();
        #pragma unroll
        for (int kc = 0; kc < 4; ++kc) {
            int s0 = half * 128 + kc * 32 + quad * 8;
            uint w0 = hist[grow * 66 + (s0 >> 2)];
            uint w1 = hist[grow * 66 + (s0 >> 2) + 1];
            short8 afr;
            ((uint*)&afr)[0] = pk((float)(w0 & 255u), (float)((w0 >> 8) & 255u));
            ((uint*)&afr)[1] = pk((float)((w0 >> 16) & 255u), (float)(w0 >> 24));
            ((uint*)&afr)[2] = pk((float)(w1 & 255u), (float)((w1 >> 8) & 255u));
            ((uint*)&afr)[3] = pk((float)((w1 >> 16) & 255u), (float)(w1 >> 24));
            #pragma unroll
            for (int ct = 0; ct < 8; ++ct) {
                int n = ct * 16 + m16;
                int chi = n >> 3, clo = n & 7;
                short8 bx;
                #pragma unroll
                for (int j = 0; j < 8; ++j) {
                    int k = kc * 32 + quad * 8 + j;
                    bx[j] = (short)Xb[(k << 7) + ((chi ^ (k & 15)) << 3) + clo];
                }
                acc[ct] = __builtin_amdgcn_mfma_f32_16x16x32_bf16(afr, bx, acc[ct], 0, 0, 0);
            }
        }
    }
    float* PBo = PS2 + (size_t)bkt * 16384;
    #pragma unroll
    for (int ct = 0; ct < 8; ++ct) {
        int n = ct * 16 + m16;
        #pragma unroll
        for (int r = 0; r < 4; ++r)
            PBo[(wave * 16 + quad * 4 + r) * 128 + n] = acc[ct][r];
    }
}

// ================= final reduce + tiny matmul =================
__global__ __launch_bounds__(128) void final_mm_kernel(const float* __restrict__ PS2,
    const float* __restrict__ w_out, const float* __restrict__ b_out,
    float* __restrict__ out)
{
    __shared__ float Sm[HDIM];
    int b = blockIdx.x, tid = threadIdx.x;
    float s0 = 0.f, s1 = 0.f, s2 = 0.f, s3 = 0.f;
    const float* base = PS2 + (size_t)b * 128 + tid;
    for (int blk = 0; blk < 512; blk += 4) {
        s0 += base[(size_t)(blk + 0) * 16384];
        s1 += base[(size_t)(blk + 1) * 16384];
        s2 += base[(size_t)(blk + 2) * 16384];
        s3 += base[(size_t)(blk + 3) * 16384];
    }
    Sm[tid] = (s0 + s1) + (s2 + s3);
    __syncthreads();
    float acc = 1024.f * b_out[tid];
    for (int k = 0; k < 128; ++k) acc += Sm[k] * w_out[k * 128 + tid];
    out[(size_t)b * HDIM + tid] = acc;
}

extern "C" void kernel_launch(void* const* d_in, const int* in_sizes, int n_in,
                              void* d_out, int out_size, void* d_ws, size_t ws_size,
                              hipStream_t stream)
{
    const int N = in_sizes[0] / HDIM;      // 131072
    const int E = in_sizes[1] / 2;         // 2097152
    const int B = N >> 10;                 // 128 graphs

    const float* x_in  = (const float*)d_in[0];
    const int*   src   = (const int*)d_in[1];
    const int*   dst   = src + E;
    const float* w_in  = (const float*)d_in[5];
    const float* b_in  = (const float*)d_in[6];
    const float* gin_w = (const float*)d_in[7];
    const float* gin_b = (const float*)d_in[8];
    const float* vt    = (const float*)d_in[9];
    const float* qkv_w = (const float*)d_in[10];
    const float* qkv_b = (const float*)d_in[11];
    const float* ao_w  = (const float*)d_in[12];
    const float* ao_b  = (const float*)d_in[13];
    const float* m_in_w   = (const float*)d_in[14];
    const float* m_conv_w = (const float*)d_in[15];
    const float* m_conv_b = (const float*)d_in[16];
    const float* m_x_w    = (const float*)d_in[17];
    const float* m_dt_w   = (const float*)d_in[18];
    const float* m_dt_b   = (const float*)d_in[19];
    const float* m_A_log  = (const float*)d_in[20];
    const float* m_D      = (const float*)d_in[21];
    const float* m_out_w  = (const float*)d_in[22];
    const float* m_norm_w = (const float*)d_in[23];
    const float* m_normf_w= (const float*)d_in[24];
    const float* w_out = (const float*)d_in[25];
    const float* b_out = (const float*)d_in[26];
    float* out = (float*)d_out;

    float* GF  = (float*)d_ws;                        // B*128
    float* P   = GF + (size_t)B * HDIM;               // 2*4*8*128
    float* PART= P + 2 * 4 * TTOK * HDIM;             // B*4*PARTSZ
    int* bcursor  = (int*)(PART + (size_t)B * 4 * PARTSZ); // 512 (dst bins)
    int* bcursor2 = bcursor + NBUCK;                  // 512 (src bins) — zeroed together
    int* count    = bcursor2 + NBUCK;                 // N
    int* starts   = count + N;                        // N+1 (padded to N+8)
    int* ssrc     = starts + N + 8;                   // E
    uint* pairbuf = (uint*)(ssrc + E);                // NBUCK*BCAP uints (dst bins, then src bins)
    float* PS2    = (float*)(pairbuf + (size_t)NBUCK * BCAP); // 512*16384 f32 partials
    ushort* AGG = (ushort*)PS2;                       // N*128 bf16 — ALIASES PS2 (AGG dead before final)
    ushort* XB0 = (ushort*)(PS2 + (size_t)NBUCK * 128 * 128); // N*128 bf16
    ushort* XB1 = XB0 + (size_t)N * HDIM;             // N*128 bf16

    const int NBB = (E + EPB - 1) / EPB;   // 512

    // ---- dst-bin + convert in one launch ----
    hipMemsetAsync(bcursor, 0, 2 * NBUCK * sizeof(int), stream);
    bin_conv_kernel<<<NBB + 2048, 256, 0, stream>>>(src, dst, bcursor, pairbuf, E,
                                                    x_in, XB0, N * 32);
    bucket_sort_kernel<<<NBUCK, 256, 0, stream>>>(pairbuf, bcursor, ssrc, starts, count, N);

    // ---- input GIN gather ∥ attn prep ∥ src-bin (pairbuf reused post-sort) ----
    gather_prep_kernel<<<2 + N / 16 + NBB, 256, 0, stream>>>(XB0, ssrc, starts, count, AGG,
                                                             vt, qkv_w, qkv_b, P,
                                                             src, dst, bcursor2, pairbuf, E);
    lin128_mfma_kernel<<<N / 128, 256, 0, stream>>>(AGG, w_in, b_in, nullptr, XB1);

    ushort* Xcur = XB1;
    ushort* Xnext = XB0;
    const int nAG = B * 4 + N / 16;   // 512 attn + 8192 gather = 8704 = 17*512
    for (int l = 0; l < 2; ++l) {
        attn_gather_kernel<<<nAG, 256, 0, stream>>>(Xcur, P + (size_t)l * 4 * TTOK * HDIM,
                                                    PART, ssrc, starts, count, AGG);
        mamba_kernel<<<B, 1024, 0, stream>>>(PART,
                                             qkv_w + (size_t)l * 128 * 384,
                                             qkv_b + (size_t)l * 384,
                                             ao_w + (size_t)l * 128 * 128,
                                             ao_b + (size_t)l * 128,
                                             m_in_w, m_conv_w, m_conv_b, m_x_w,
                                             m_dt_w, m_dt_b, m_A_log, m_D, m_out_w,
                                             m_norm_w, m_normf_w, GF);
        lin128_mfma_kernel<<<N / 128, 256, 0, stream>>>(AGG, gin_w + (size_t)l * 128 * 128,
                                                        gin_b + (size_t)l * 128, GF, Xnext);
        ushort* t = Xcur; Xcur = Xnext; Xnext = t;
    }

    // ---- final GIN + segment_sum: counts-MFMA partials + tiny matmul (overwrites AGG) ----
    final_count_kernel<<<NBUCK, 512, 0, stream>>>(Xcur, pairbuf, bcursor2, PS2);
    final_mm_kernel<<<B, 128, 0, stream>>>(PS2, w_out, b_out, out);

    (void)n_in; (void)out_size; (void)ws_size;
}

// Round 8
// 793.298 us; speedup vs baseline: 1.2127x; 1.0378x over previous
//
#include <hip/hip_runtime.h>

#define HDIM 128
#define TTOK 8
#define NPG 1024
#define NBUCK 512
#define BSHIFT 8
#define BCAP 5120
#define EPB 4096
#define PARTSZ 4160   // per (graph,part): 32*128 O + 32 m + 32 l

typedef unsigned short ushort;
typedef unsigned int uint;
typedef __attribute__((ext_vector_type(8))) short short8;
typedef __attribute__((ext_vector_type(4))) float f32x4;

__device__ __forceinline__ ushort f2bf(float f) {
    unsigned int x = __float_as_uint(f);
    return (ushort)((x + 0x7FFFu + ((x >> 16) & 1u)) >> 16);
}
__device__ __forceinline__ float blo(uint u) { return __uint_as_float(u << 16); }
__device__ __forceinline__ float bhi(uint u) { return __uint_as_float(u & 0xFFFF0000u); }
__device__ __forceinline__ uint pk(float a, float b) {
    return (uint)f2bf(a) | ((uint)f2bf(b) << 16);
}

// ================= bin body (mode 0: key=dst pay=src; mode 1: key=src pay=graph(dst)) =================
__device__ __forceinline__ void bin_body(const int* __restrict__ src,
    const int* __restrict__ dst, int mode, int* __restrict__ bcursor,
    uint* __restrict__ pairbuf, int E, int e0, int tid,
    int* lcnt, int* lbase)
{
    for (int i = tid; i < NBUCK; i += 256) lcnt[i] = 0;
    __syncthreads();
    uint pkd[16];
    int bk[16], rk[16];
    #pragma unroll
    for (int i = 0; i < 16; ++i) {
        int e = e0 + i * 256 + tid;
        int s = (e < E) ? src[e] : 0;
        int d = (e < E) ? dst[e] : 0;
        int key = mode ? s : d;
        uint pay = mode ? (uint)(d >> 10) : (uint)s;
        if (e >= E) key = -1;
        int b = key >> BSHIFT;
        bk[i] = b;
        pkd[i] = ((uint)(key & 255) << 17) | pay;
        rk[i] = (key >= 0) ? atomicAdd(&lcnt[b], 1) : 0;
    }
    __syncthreads();
    for (int i = tid; i < NBUCK; i += 256) {
        int c = lcnt[i];
        lbase[i] = c ? atomicAdd(&bcursor[i], c) : 0;
    }
    __syncthreads();
    #pragma unroll
    for (int i = 0; i < 16; ++i) {
        if (bk[i] >= 0) {
            int slot = lbase[bk[i]] + rk[i];
            if (slot < BCAP) pairbuf[(size_t)bk[i] * BCAP + slot] = pkd[i];
        }
    }
}

// ================= dst-bin + f32->bf16 convert, one launch =================
__global__ __launch_bounds__(256) void bin_conv_kernel(const int* __restrict__ src,
    const int* __restrict__ dst, int* __restrict__ bcursor, uint* __restrict__ pairbuf,
    int E, const float* __restrict__ xin, ushort* __restrict__ outb, int n4)
{
    __shared__ int lcnt[NBUCK];
    __shared__ int lbase[NBUCK];
    int tid = threadIdx.x;
    int b = blockIdx.x;
    if (b < NBUCK) {
        bin_body(src, dst, 0, bcursor, pairbuf, E, b * EPB, tid, lcnt, lbase);
    } else {
        for (int i = (b - NBUCK) * 256 + tid; i < n4; i += 2048 * 256) {
            float4 v = ((const float4*)xin)[i];
            uint2 o;
            o.x = pk(v.x, v.y); o.y = pk(v.z, v.w);
            ((uint2*)outb)[i] = o;
        }
    }
}

// ================= Pass B (dst-sort): one block per bucket; self-scans bucket counts =================
__global__ __launch_bounds__(256) void bucket_sort_kernel(const uint* __restrict__ pairbuf,
    const int* __restrict__ bcount,
    int* __restrict__ ssrc, int* __restrict__ starts, int* __restrict__ countn, int N)
{
    __shared__ int sc[NBUCK];
    __shared__ int lcount[256];
    __shared__ int lcur[256];
    __shared__ int lss[BCAP];   // 20 KB
    int b = blockIdx.x;
    int tid = threadIdx.x;
    sc[tid] = min(bcount[tid], BCAP);
    sc[tid + 256] = min(bcount[tid + 256], BCAP);
    lcount[tid] = 0;
    __syncthreads();
    for (int off = 1; off < NBUCK; off <<= 1) {
        int a0 = (tid >= off) ? sc[tid - off] : 0;
        int a1 = (tid + 256 >= off) ? sc[tid + 256 - off] : 0;
        __syncthreads();
        sc[tid] += a0; sc[tid + 256] += a1;
        __syncthreads();
    }
    int nb = min(bcount[b], BCAP);
    int base = sc[b] - nb;
    const uint* pp = pairbuf + (size_t)b * BCAP;
    for (int i = tid; i < nb; i += 256)
        atomicAdd(&lcount[(pp[i] >> 17) & 255], 1);
    __syncthreads();
    int v = lcount[tid];
    lcur[tid] = v;
    __syncthreads();
    for (int off = 1; off < 256; off <<= 1) {
        int t = (tid >= off) ? lcur[tid - off] : 0;
        __syncthreads();
        lcur[tid] += t;
        __syncthreads();
    }
    int excl = lcur[tid] - v;
    int node = b * 256 + tid;
    starts[node] = base + excl;
    countn[node] = v;
    __syncthreads();
    lcur[tid] = excl;
    __syncthreads();
    for (int i = tid; i < nb; i += 256) {
        uint p = pp[i];
        int pos = atomicAdd(&lcur[(p >> 17) & 255], 1);
        lss[pos] = (int)(p & 0x1FFFFu);
    }
    __syncthreads();
    for (int i = tid; i < nb; i += 256) ssrc[base + i] = lss[i];
    if (b == NBUCK - 1 && tid == 0) starts[N] = base + nb;
}

// ================= gather body: 16 nodes, 16 lanes each, 8-deep ILP =================
__device__ __forceinline__ void gather16_body(const ushort* __restrict__ XS,
    const int* __restrict__ ssrc, const int* __restrict__ starts,
    const int* __restrict__ count, ushort* __restrict__ AGG, int nbase, int tid)
{
    int g = tid >> 4, lane = tid & 15;
    int node = nbase + g;
    uint4 sv = *((const uint4*)(XS + (size_t)node * HDIM) + lane);
    float a0 = blo(sv.x), a1 = bhi(sv.x), a2 = blo(sv.y), a3 = bhi(sv.y);
    float a4 = blo(sv.z), a5 = bhi(sv.z), a6 = blo(sv.w), a7 = bhi(sv.w);
    int s0 = starts[node], cn = count[node];
    for (int j0 = 0; j0 < cn; j0 += 16) {
        int myid = (j0 + lane < cn) ? ssrc[s0 + j0 + lane] : 0;
        int m = min(16, cn - j0);
        int j = 0;
        for (; j + 7 < m; j += 8) {
            uint4 u[8];
            #pragma unroll
            for (int q = 0; q < 8; ++q) {
                int sidx = __shfl(myid, j + q, 16);
                u[q] = *((const uint4*)(XS + (size_t)sidx * HDIM) + lane);
            }
            #pragma unroll
            for (int q = 0; q < 8; ++q) {
                a0 += blo(u[q].x); a1 += bhi(u[q].x);
                a2 += blo(u[q].y); a3 += bhi(u[q].y);
                a4 += blo(u[q].z); a5 += bhi(u[q].z);
                a6 += blo(u[q].w); a7 += bhi(u[q].w);
            }
        }
        for (; j + 3 < m; j += 4) {
            uint4 u[4];
            #pragma unroll
            for (int q = 0; q < 4; ++q) {
                int sidx = __shfl(myid, j + q, 16);
                u[q] = *((const uint4*)(XS + (size_t)sidx * HDIM) + lane);
            }
            #pragma unroll
            for (int q = 0; q < 4; ++q) {
                a0 += blo(u[q].x); a1 += bhi(u[q].x);
                a2 += blo(u[q].y); a3 += bhi(u[q].y);
                a4 += blo(u[q].z); a5 += bhi(u[q].z);
                a6 += blo(u[q].w); a7 += bhi(u[q].w);
            }
        }
        for (; j < m; ++j) {
            int sidx = __shfl(myid, j, 16);
            uint4 ua = *((const uint4*)(XS + (size_t)sidx * HDIM) + lane);
            a0 += blo(ua.x); a1 += bhi(ua.x);
            a2 += blo(ua.y); a3 += bhi(ua.y);
            a4 += blo(ua.z); a5 += bhi(ua.z);
            a6 += blo(ua.w); a7 += bhi(ua.w);
        }
    }
    uint4 o;
    o.x = pk(a0, a1); o.y = pk(a2, a3); o.z = pk(a4, a5); o.w = pk(a6, a7);
    *((uint4*)(AGG + (size_t)node * HDIM) + lane) = o;
}

// ================= input-GIN gather ∥ attn-prep ∥ src-bin (one dispatch) =================
// blocks 0-1: attn P prep (long; scheduled first); [2, 2+8192): gather; [8194, 8706): src-bin.
__global__ __launch_bounds__(256) void gather_prep_kernel(const ushort* __restrict__ XS,
    const int* __restrict__ ssrc, const int* __restrict__ starts,
    const int* __restrict__ count, ushort* __restrict__ AGG,
    const float* __restrict__ vt, const float* __restrict__ qkv_w,
    const float* __restrict__ qkv_b, float* __restrict__ P,
    const int* __restrict__ src, const int* __restrict__ dst,
    int* __restrict__ bcursor2, uint* __restrict__ pairbuf, int E)
{
    __shared__ float vtl[TTOK][HDIM];
    __shared__ float q[TTOK][HDIM];
    __shared__ int lcnt[NBUCK];
    __shared__ int lbase[NBUCK];
    int b = blockIdx.x, tid = threadIdx.x;
    if (b < 2) {
        int l = b;
        const float* vtp = vt + (size_t)l * TTOK * HDIM;
        const float* qw = qkv_w + (size_t)l * 128 * 384;
        const float* qb = qkv_b + (size_t)l * 384;
        float* Pp = P + (size_t)l * 4 * TTOK * HDIM;
        for (int i = tid; i < TTOK * HDIM; i += 256) vtl[i >> 7][i & 127] = vtp[i];
        __syncthreads();
        for (int i = tid; i < TTOK * HDIM; i += 256) {
            int t = i >> 7, j = i & 127;
            float acc = qb[j];
            for (int c = 0; c < 128; ++c) acc += vtl[t][c] * qw[c * 384 + j];
            q[t][j] = acc;
        }
        __syncthreads();
        const float scale = 0.17677669529663687f; // 1/sqrt(32)
        for (int i = tid; i < 4 * TTOK * HDIM; i += 256) {
            int h = i >> 10, t = (i >> 7) & 7, cc = i & 127;
            float acc = 0.f;
            for (int d = 0; d < 32; ++d)
                acc += qw[cc * 384 + 128 + h * 32 + d] * q[t][h * 32 + d];
            Pp[i] = acc * scale;
        }
    } else if (b < 8194) {
        gather16_body(XS, ssrc, starts, count, AGG, (b - 2) * 16, tid);
    } else {
        bin_body(src, dst, 1, bcursor2, pairbuf, E, (b - 8194) * EPB, tid, lcnt, lbase);
    }
}

// ================= attention body v3: 64-node tiles, ~25.2 KB LDS (St/P union) =================
__device__ __forceinline__ void attn_body(const ushort* __restrict__ X,
    const float* __restrict__ P, float* __restrict__ PART, int bp, int tid)
{
    __shared__ ushort Xl[64 * 128];    // 16 KB swizzled X tile (64 nodes)
    __shared__ float  StU[32 * 68];    // 8.5 KB union: prologue-P bf16 / scores f32 / exp-P bf16
    __shared__ float lm[32], ll[32], lalpha[32];
    ushort* PlU = (ushort*)StU;
    int b = bp >> 2, part = bp & 3;
    int wave = tid >> 6, lane = tid & 63;
    int m16 = lane & 15, quad = lane >> 4;

    for (int i = tid; i < 2048; i += 256) {
        float2 v = *(const float2*)(P + (size_t)i * 2);
        ((uint*)PlU)[i] = pk(v.x, v.y);
    }
    if (tid < 32) { lm[tid] = -1e30f; ll[tid] = 0.f; }
    __syncthreads();
    short8 aP[2][4];
    #pragma unroll
    for (int mt = 0; mt < 2; ++mt)
        #pragma unroll
        for (int kc = 0; kc < 4; ++kc)
            aP[mt][kc] = *(const short8*)&PlU[(mt * 16 + m16) * 128 + (kc * 4 + quad) * 8];
    __syncthreads();

    f32x4 oacc[2][2] = {};
    const uint4* xsg = (const uint4*)(X + (size_t)b * NPG * HDIM);

    for (int tt = 0; tt < 4; ++tt) {
        {
            const uint4* xs = xsg + (part * 4 + tt) * 1024;
            uint4* xl = (uint4*)Xl;
            for (int i = tid; i < 1024; i += 256) {
                int row = i >> 4, cc = i & 15;
                xl[row * 16 + (cc ^ (row & 15))] = xs[i];
            }
        }
        __syncthreads();
        {
            f32x4 sacc[2] = {};
            #pragma unroll
            for (int kc = 0; kc < 4; ++kc) {
                int node = wave * 16 + m16;
                short8 bx = *(const short8*)&Xl[node * 128 + (((kc * 4 + quad) ^ m16) << 3)];
                sacc[0] = __builtin_amdgcn_mfma_f32_16x16x32_bf16(aP[0][kc], bx, sacc[0], 0, 0, 0);
                sacc[1] = __builtin_amdgcn_mfma_f32_16x16x32_bf16(aP[1][kc], bx, sacc[1], 0, 0, 0);
            }
            #pragma unroll
            for (int mt = 0; mt < 2; ++mt)
                #pragma unroll
                for (int r = 0; r < 4; ++r)
                    StU[(mt * 16 + quad * 4 + r) * 68 + wave * 16 + m16] = sacc[mt][r];
        }
        __syncthreads();
        {
            int j = tid >> 3, g = tid & 7;
            const float* rowp = &StU[j * 68 + g * 8];
            float4 v0 = *(const float4*)(rowp);
            float4 v1 = *(const float4*)(rowp + 4);
            float mx = fmaxf(fmaxf(fmaxf(v0.x, v0.y), fmaxf(v0.z, v0.w)),
                             fmaxf(fmaxf(v1.x, v1.y), fmaxf(v1.z, v1.w)));
            mx = fmaxf(mx, __shfl_down(mx, 4, 8));
            mx = fmaxf(mx, __shfl_down(mx, 2, 8));
            mx = fmaxf(mx, __shfl_down(mx, 1, 8));
            mx = __shfl(mx, 0, 8);
            float mold = lm[j];
            float Mn = fmaxf(mold, mx);
            float alpha = __expf(mold - Mn);
            float p0 = __expf(v0.x - Mn), p1 = __expf(v0.y - Mn);
            float p2 = __expf(v0.z - Mn), p3 = __expf(v0.w - Mn);
            float p4 = __expf(v1.x - Mn), p5 = __expf(v1.y - Mn);
            float p6 = __expf(v1.z - Mn), p7 = __expf(v1.w - Mn);
            float s = ((p0 + p1) + (p2 + p3)) + ((p4 + p5) + (p6 + p7));
            s += __shfl_down(s, 4, 8);
            s += __shfl_down(s, 2, 8);
            s += __shfl_down(s, 1, 8);
            if (g == 0) {
                ll[j] = ll[j] * alpha + s;
                lm[j] = Mn;
                lalpha[j] = alpha;
            }
            __syncthreads();   // all St reads complete before exp-P overwrites the union
            uint4 u0;
            u0.x = pk(p0, p1); u0.y = pk(p2, p3); u0.z = pk(p4, p5); u0.w = pk(p6, p7);
            ((uint4*)PlU)[j * 8 + (g ^ (j & 7))] = u0;   // exp-P [32][64], chunk-swizzled
        }
        __syncthreads();
        {
            #pragma unroll
            for (int mt = 0; mt < 2; ++mt)
                #pragma unroll
                for (int r = 0; r < 4; ++r) {
                    float a = lalpha[mt * 16 + quad * 4 + r];
                    oacc[mt][0][r] *= a;
                    oacc[mt][1][r] *= a;
                }
            #pragma unroll
            for (int kc = 0; kc < 2; ++kc) {
                short8 ap2[2], bx[2];
                #pragma unroll
                for (int mt = 0; mt < 2; ++mt)
                    ap2[mt] = *(const short8*)&PlU[(mt * 16 + m16) * 64
                                                   + (((kc * 4 + quad) ^ (m16 & 7)) << 3)];
                #pragma unroll
                for (int ntl = 0; ntl < 2; ++ntl) {
                    int cf = (2 * wave + ntl) * 16 + m16;
                    int chi = cf >> 3, clo = cf & 7;
                    short8 v;
                    #pragma unroll
                    for (int jj = 0; jj < 8; ++jj) {
                        int row = kc * 32 + quad * 8 + jj;
                        v[jj] = (short)Xl[(row << 7) + ((chi ^ (row & 15)) << 3) + clo];
                    }
                    bx[ntl] = v;
                }
                #pragma unroll
                for (int mt = 0; mt < 2; ++mt)
                    #pragma unroll
                    for (int ntl = 0; ntl < 2; ++ntl)
                        oacc[mt][ntl] = __builtin_amdgcn_mfma_f32_16x16x32_bf16(
                            ap2[mt], bx[ntl], oacc[mt][ntl], 0, 0, 0);
            }
        }
        __syncthreads();
    }
    float* PB = PART + ((size_t)b * 4 + part) * PARTSZ;
    #pragma unroll
    for (int mt = 0; mt < 2; ++mt)
        #pragma unroll
        for (int r = 0; r < 4; ++r) {
            int j = mt * 16 + quad * 4 + r;
            PB[j * 128 + (2 * wave + 0) * 16 + m16] = oacc[mt][0][r];
            PB[j * 128 + (2 * wave + 1) * 16 + m16] = oacc[mt][1][r];
        }
    if (tid < 32) { PB[4096 + tid] = lm[tid]; PB[4128 + tid] = ll[tid]; }
}

// ================= combined attention ∥ gather (independent work, one dispatch) =================
__global__ __launch_bounds__(256) void attn_gather_kernel(const ushort* __restrict__ X,
    const float* __restrict__ P, float* __restrict__ PART,
    const int* __restrict__ ssrc, const int* __restrict__ starts,
    const int* __restrict__ count, ushort* __restrict__ AGG)
{
    int bp = blockIdx.x;
    if (bp % 17 == 0) {
        attn_body(X, P, PART, bp / 17, threadIdx.x);
    } else {
        int gidx = bp - bp / 17 - 1;
        gather16_body(X, ssrc, starts, count, AGG, gidx * 16, threadIdx.x);
    }
}

// ================= MFMA linear (bf16 in/out): XD = XS @ W + b [+ GF[row>>10]] =================
__global__ __launch_bounds__(256) void lin128_mfma_kernel(const ushort* __restrict__ XS,
    const float* __restrict__ W, const float* __restrict__ bias,
    const float* __restrict__ GF, ushort* __restrict__ XD)
{
    __shared__ ushort Xl[128 * 128];
    __shared__ ushort Wl[128 * 128];
    int tid = threadIdx.x;
    size_t r0 = (size_t)blockIdx.x * 128;
    {
        const uint4* xs = (const uint4*)(XS + r0 * HDIM);
        uint4* xl = (uint4*)Xl;
        for (int i = tid; i < 2048; i += 256) {
            int row = i >> 4, cc = i & 15;
            xl[row * 16 + (cc ^ (row & 15))] = xs[i];
        }
    }
    {
        uint4* wl = (uint4*)Wl;
        for (int i = tid; i < 2048; i += 256) {
            int n = i & 127, c = i >> 7;
            const float* wp = W + (size_t)(c * 8) * 128 + n;
            float w0 = wp[0], w1 = wp[128], w2 = wp[256], w3 = wp[384];
            float w4 = wp[512], w5 = wp[640], w6 = wp[768], w7 = wp[896];
            uint4 u;
            u.x = pk(w0, w1); u.y = pk(w2, w3); u.z = pk(w4, w5); u.w = pk(w6, w7);
            wl[n * 16 + (c ^ (n & 15))] = u;
        }
    }
    __syncthreads();
    int wave = tid >> 6;
    int lane = tid & 63;
    int m16 = lane & 15, quad = lane >> 4;
    const short8* Xf = (const short8*)Xl;
    const short8* Wf = (const short8*)Wl;
    short8 afr[2][4];
    #pragma unroll
    for (int rt = 0; rt < 2; ++rt)
        #pragma unroll
        for (int kc = 0; kc < 4; ++kc)
            afr[rt][kc] = Xf[(wave * 32 + rt * 16 + m16) * 16 + ((kc * 4 + quad) ^ m16)];
    int graph = (int)(r0 >> 10);
    #pragma unroll
    for (int ct = 0; ct < 8; ++ct) {
        int col = ct * 16 + m16;
        short8 bfr[4];
        #pragma unroll
        for (int kc = 0; kc < 4; ++kc)
            bfr[kc] = Wf[col * 16 + ((kc * 4 + quad) ^ m16)];
        f32x4 acc0 = {0.f, 0.f, 0.f, 0.f};
        f32x4 acc1 = {0.f, 0.f, 0.f, 0.f};
        #pragma unroll
        for (int kc = 0; kc < 4; ++kc) {
            acc0 = __builtin_amdgcn_mfma_f32_16x16x32_bf16(afr[0][kc], bfr[kc], acc0, 0, 0, 0);
            acc1 = __builtin_amdgcn_mfma_f32_16x16x32_bf16(afr[1][kc], bfr[kc], acc1, 0, 0, 0);
        }
        float add = bias[col] + (GF ? GF[(size_t)graph * HDIM + col] : 0.f);
        #pragma unroll
        for (int r = 0; r < 4; ++r) {
            XD[(r0 + wave * 32 + quad * 4 + r) * HDIM + col] = f2bf(acc0[r] + add);
            XD[(r0 + wave * 32 + 16 + quad * 4 + r) * HDIM + col] = f2bf(acc1[r] + add);
        }
    }
}

// ================= mamba (R5 layout: strided-per-thread = wave-coalesced weights) =================
__global__ __launch_bounds__(1024) void mamba_kernel(const float* __restrict__ PART,
    const float* __restrict__ qkv_w, const float* __restrict__ qkv_b,
    const float* __restrict__ ao_w, const float* __restrict__ ao_b,
    const float* __restrict__ in_w, const float* __restrict__ conv_w,
    const float* __restrict__ conv_b, const float* __restrict__ x_w,
    const float* __restrict__ dt_w, const float* __restrict__ dt_b,
    const float* __restrict__ A_log, const float* __restrict__ Dp,
    const float* __restrict__ out_w, const float* __restrict__ norm_w,
    const float* __restrict__ normf_w, float* __restrict__ GF)
{
    constexpr int I = 256, S = 16;
    __shared__ float R[32 * 132];
    __shared__ float wgt[4][32];
    __shared__ float inv[32];
    __shared__ float tok[TTOK][HDIM];
    __shared__ float hn[TTOK][HDIM];
    __shared__ float uu[TTOK][I];
    __shared__ float gg[TTOK][I];
    __shared__ float ssm[TTOK][40];
    __shared__ float yy[TTOK][I];
    int b = blockIdx.x, tid = threadIdx.x;

    const float* PB = PART + (size_t)b * 4 * PARTSZ;
    if (tid < 32) {
        int j = tid;
        float m0 = PB[4096 + j], m1 = PB[PARTSZ + 4096 + j];
        float m2 = PB[2 * PARTSZ + 4096 + j], m3 = PB[3 * PARTSZ + 4096 + j];
        float M = fmaxf(fmaxf(m0, m1), fmaxf(m2, m3));
        float w0 = __expf(m0 - M), w1 = __expf(m1 - M);
        float w2 = __expf(m2 - M), w3 = __expf(m3 - M);
        float L = w0 * PB[4128 + j] + w1 * PB[PARTSZ + 4128 + j]
                + w2 * PB[2 * PARTSZ + 4128 + j] + w3 * PB[3 * PARTSZ + 4128 + j];
        wgt[0][j] = w0; wgt[1][j] = w1; wgt[2][j] = w2; wgt[3][j] = w3;
        inv[j] = 1.f / L;
    }
    __syncthreads();
    #pragma unroll
    for (int it = 0; it < 4; ++it) {
        int idx = it * 1024 + tid;
        int j = idx >> 7, c = idx & 127;
        float v = wgt[0][j] * PB[idx] + wgt[1][j] * PB[PARTSZ + idx]
                + wgt[2][j] * PB[2 * PARTSZ + idx] + wgt[3][j] * PB[3 * PARTSZ + idx];
        R[j * 132 + c] = v * inv[j];
    }
    __syncthreads();
    {
        int t = tid >> 7, col = tid & 127;
        int h = col >> 5;
        const float* rp = &R[(h * 8 + t) * 132];
        const float* wp = qkv_w + 256 + col;
        float acc = qkv_b[256 + col];
        for (int c = 0; c < 128; c += 8) {
            float w[8];
            #pragma unroll
            for (int q = 0; q < 8; ++q) w[q] = wp[(size_t)(c + q) * 384];
            #pragma unroll
            for (int q = 0; q < 8; ++q) acc += rp[c + q] * w[q];
        }
        hn[t][col] = acc;
    }
    __syncthreads();
    {
        int t = tid >> 7, col = tid & 127;
        const float* hp = hn[t];
        const float* wp = ao_w + col;
        float acc = ao_b[col];
        for (int k = 0; k < 128; k += 8) {
            float w[8];
            #pragma unroll
            for (int q = 0; q < 8; ++q) w[q] = wp[(size_t)(k + q) * 128];
            #pragma unroll
            for (int q = 0; q < 8; ++q) acc += hp[k + q] * w[q];
        }
        tok[t][col] = acc;
    }
    __syncthreads();

    if (tid < 512) {
        int t = tid >> 6, lane = tid & 63;
        float v0 = tok[t][lane], v1 = tok[t][lane + 64];
        float s = v0 * v0 + v1 * v1;
        #pragma unroll
        for (int off = 32; off; off >>= 1) s += __shfl_down(s, off);
        s = __shfl(s, 0);
        float r = rsqrtf(s * (1.f / 128.f) + 1e-5f);
        hn[t][lane] = v0 * r * norm_w[lane];
        hn[t][lane + 64] = v1 * r * norm_w[lane + 64];
    }
    __syncthreads();
    {
        int j = tid & 511, tq = tid >> 9;
        float acc[4] = {0.f, 0.f, 0.f, 0.f};
        const float* wp = in_w + j;
        for (int c = 0; c < 128; c += 8) {
            float w[8];
            #pragma unroll
            for (int q = 0; q < 8; ++q) w[q] = wp[(size_t)(c + q) * 512];
            #pragma unroll
            for (int q = 0; q < 8; ++q) {
                float wq = w[q];
                #pragma unroll
                for (int k = 0; k < 4; ++k) acc[k] += hn[tq * 4 + k][c + q] * wq;
            }
        }
        if (j < 256) {
            #pragma unroll
            for (int k = 0; k < 4; ++k) uu[tq * 4 + k][j] = acc[k];
        } else {
            #pragma unroll
            for (int k = 0; k < 4; ++k) gg[tq * 4 + k][j - 256] = acc[k];
        }
    }
    __syncthreads();
    if (tid < 256) {
        int i = tid;
        float cw0 = conv_w[i * 4 + 0], cw1 = conv_w[i * 4 + 1];
        float cw2 = conv_w[i * 4 + 2], cw3 = conv_w[i * 4 + 3];
        float cb = conv_b[i];
        float uv[TTOK];
        #pragma unroll
        for (int t = 0; t < TTOK; ++t) uv[t] = uu[t][i];
        #pragma unroll
        for (int t = 0; t < TTOK; ++t) {
            float a = cw3 * uv[t] + cb;
            if (t >= 1) a += cw2 * uv[t - 1];
            if (t >= 2) a += cw1 * uv[t - 2];
            if (t >= 3) a += cw0 * uv[t - 3];
            float sg = 1.f / (1.f + __expf(-a));
            uu[t][i] = a * sg;
        }
    }
    __syncthreads();
    {
        int t = tid >> 7, j = tid & 127;
        if (j < 40) {
            float acc = 0.f;
            const float* wp = x_w + j;
            const float* up = uu[t];
            for (int c = 0; c < 256; c += 8) {
                float w[8];
                #pragma unroll
                for (int q = 0; q < 8; ++q) w[q] = wp[(size_t)(c + q) * 40];
                #pragma unroll
                for (int q = 0; q < 8; ++q) acc += up[c + q] * w[q];
            }
            ssm[t][j] = acc;
        }
    }
    __syncthreads();
    if (tid < 256) {
        int i = tid;
        float dw[8];
        #pragma unroll
        for (int r = 0; r < 8; ++r) dw[r] = dt_w[r * 256 + i];
        float dtbias = dt_b[i];
        float a[S], st[S];
        #pragma unroll
        for (int s = 0; s < S; ++s) { a[s] = -__expf(A_log[i * S + s]); st[s] = 0.f; }
        float Di = Dp[i];
        for (int t = 0; t < TTOK; ++t) {
            float d = dtbias;
            #pragma unroll
            for (int r = 0; r < 8; ++r) d += ssm[t][r] * dw[r];
            d = (d > 20.f) ? d : log1pf(__expf(d));
            float ut = uu[t][i];
            float du = d * ut;
            float y = 0.f;
            #pragma unroll
            for (int s = 0; s < S; ++s) {
                float dA = __expf(d * a[s]);
                st[s] = dA * st[s] + du * ssm[t][8 + s];
                y += st[s] * ssm[t][24 + s];
            }
            y += ut * Di;
            float g = gg[t][i];
            float sg = 1.f / (1.f + __expf(-g));
            yy[t][i] = y * g * sg;
        }
    }
    __syncthreads();
    {
        int t = tid >> 7, c = tid & 127;
        float acc = tok[t][c];
        const float* wp = out_w + c;
        const float* yp = yy[t];
        for (int i = 0; i < 256; i += 8) {
            float w[8];
            #pragma unroll
            for (int q = 0; q < 8; ++q) w[q] = wp[(size_t)(i + q) * 128];
            #pragma unroll
            for (int q = 0; q < 8; ++q) acc += yp[i + q] * w[q];
        }
        hn[t][c] = acc;
    }
    __syncthreads();
    if (tid < 512) {
        int t = tid >> 6, lane = tid & 63;
        float v0 = hn[t][lane], v1 = hn[t][lane + 64];
        float s = v0 * v0 + v1 * v1;
        #pragma unroll
        for (int off = 32; off; off >>= 1) s += __shfl_down(s, off);
        s = __shfl(s, 0);
        float r = rsqrtf(s * (1.f / 128.f) + 1e-5f);
        hn[t][lane] = v0 * r * normf_w[lane];
        hn[t][lane + 64] = v1 * r * normf_w[lane + 64];
    }
    __syncthreads();
    if (tid < 128) {
        float s = 0.f;
        #pragma unroll
        for (int t = 0; t < TTOK; ++t) s += hn[t][tid];
        GF[(size_t)b * HDIM + tid] = s * (1.f / TTOK);
    }
}

// ================= final: per-src-bucket u8 count histogram + MFMA counts@X =================
// Writes TRANSPOSED partials PS2T[g][bkt][c] so the reducer reads each graph contiguously.
__global__ __launch_bounds__(512) void final_count_kernel(const ushort* __restrict__ X,
    const uint* __restrict__ pairbuf, const int* __restrict__ bcount,
    float* __restrict__ PS2)
{
    __shared__ uint hist[128 * 66];     // u8 counts [graph][src/4], padded: 33 KB
    __shared__ ushort Xb[128 * 128];    // 32 KB swizzled half-tile
    int bkt = blockIdx.x, tid = threadIdx.x;
    for (int i = tid; i < 128 * 66; i += 512) hist[i] = 0u;
    __syncthreads();
    int nb = min(bcount[bkt], BCAP);
    const uint* pp = pairbuf + (size_t)bkt * BCAP;
    for (int i = tid; i < nb; i += 512) {
        uint p = pp[i];
        int g = (int)(p & 0x1FFFFu);
        int s = (int)((p >> 17) & 255);
        atomicAdd(&hist[g * 66 + (s >> 2)], 1u << ((s & 3) * 8));
    }
    if (tid < 256) {                          // self term
        int g = bkt >> 2;
        atomicAdd(&hist[g * 66 + (tid >> 2)], 1u << ((tid & 3) * 8));
    }
    int wave = tid >> 6, lane = tid & 63;
    int m16 = lane & 15, quad = lane >> 4;
    int grow = wave * 16 + m16;
    f32x4 acc[8] = {};
    for (int half = 0; half < 2; ++half) {
        __syncthreads();
        {
            const uint4* xs = (const uint4*)(X + ((size_t)bkt * 256 + half * 128) * HDIM);
            uint4* xl = (uint4*)Xb;
            for (int i = tid; i < 2048; i += 512) {
                int row = i >> 4, cc = i & 15;
                xl[row * 16 + (cc ^ (row & 15))] = xs[i];
            }
        }
        __syncthreads();
        #pragma unroll
        for (int kc = 0; kc < 4; ++kc) {
            int s0 = half * 128 + kc * 32 + quad * 8;
            uint w0 = hist[grow * 66 + (s0 >> 2)];
            uint w1 = hist[grow * 66 + (s0 >> 2) + 1];
            short8 afr;
            ((uint*)&afr)[0] = pk((float)(w0 & 255u), (float)((w0 >> 8) & 255u));
            ((uint*)&afr)[1] = pk((float)((w0 >> 16) & 255u), (float)(w0 >> 24));
            ((uint*)&afr)[2] = pk((float)(w1 & 255u), (float)((w1 >> 8) & 255u));
            ((uint*)&afr)[3] = pk((float)((w1 >> 16) & 255u), (float)(w1 >> 24));
            #pragma unroll
            for (int ct = 0; ct < 8; ++ct) {
                int n = ct * 16 + m16;
                int chi = n >> 3, clo = n & 7;
                short8 bx;
                #pragma unroll
                for (int j = 0; j < 8; ++j) {
                    int k = kc * 32 + quad * 8 + j;
                    bx[j] = (short)Xb[(k << 7) + ((chi ^ (k & 15)) << 3) + clo];
                }
                acc[ct] = __builtin_amdgcn_mfma_f32_16x16x32_bf16(afr, bx, acc[ct], 0, 0, 0);
            }
        }
    }
    // transposed write: PS2T[g][bkt][c], g = wave*16+quad*4+r, c = ct*16+m16
    #pragma unroll
    for (int ct = 0; ct < 8; ++ct) {
        int n = ct * 16 + m16;
        #pragma unroll
        for (int r = 0; r < 4; ++r)
            PS2[(size_t)(wave * 16 + quad * 4 + r) * (NBUCK * 128)
                + (size_t)bkt * 128 + n] = acc[ct][r];
    }
}

// ================= final: contiguous reduce over buckets + tiny matmul (one block/graph) =================
__global__ __launch_bounds__(512) void final_mm_kernel(const float* __restrict__ PS2,
    const float* __restrict__ w_out, const float* __restrict__ b_out,
    float* __restrict__ out)
{
    __shared__ float red[4][128];
    __shared__ float Sm[HDIM];
    int b = blockIdx.x, tid = threadIdx.x;
    int c = tid & 127, q = tid >> 7;
    const float* base = PS2 + (size_t)b * (NBUCK * 128) + c;
    float s0 = 0.f, s1 = 0.f, s2 = 0.f, s3 = 0.f;
    int k0 = q * 128;
    for (int k = k0; k < k0 + 128; k += 4) {
        s0 += base[(size_t)(k + 0) * 128];
        s1 += base[(size_t)(k + 1) * 128];
        s2 += base[(size_t)(k + 2) * 128];
        s3 += base[(size_t)(k + 3) * 128];
    }
    red[q][c] = (s0 + s1) + (s2 + s3);
    __syncthreads();
    if (tid < 128) {
        Sm[tid] = (red[0][tid] + red[1][tid]) + (red[2][tid] + red[3][tid]);
    }
    __syncthreads();
    if (tid < 128) {
        float acc = 1024.f * b_out[tid];
        for (int k = 0; k < 128; ++k) acc += Sm[k] * w_out[k * 128 + tid];
        out[(size_t)b * HDIM + tid] = acc;
    }
}

extern "C" void kernel_launch(void* const* d_in, const int* in_sizes, int n_in,
                              void* d_out, int out_size, void* d_ws, size_t ws_size,
                              hipStream_t stream)
{
    const int N = in_sizes[0] / HDIM;      // 131072
    const int E = in_sizes[1] / 2;         // 2097152
    const int B = N >> 10;                 // 128 graphs

    const float* x_in  = (const float*)d_in[0];
    const int*   src   = (const int*)d_in[1];
    const int*   dst   = src + E;
    const float* w_in  = (const float*)d_in[5];
    const float* b_in  = (const float*)d_in[6];
    const float* gin_w = (const float*)d_in[7];
    const float* gin_b = (const float*)d_in[8];
    const float* vt    = (const float*)d_in[9];
    const float* qkv_w = (const float*)d_in[10];
    const float* qkv_b = (const float*)d_in[11];
    const float* ao_w  = (const float*)d_in[12];
    const float* ao_b  = (const float*)d_in[13];
    const float* m_in_w   = (const float*)d_in[14];
    const float* m_conv_w = (const float*)d_in[15];
    const float* m_conv_b = (const float*)d_in[16];
    const float* m_x_w    = (const float*)d_in[17];
    const float* m_dt_w   = (const float*)d_in[18];
    const float* m_dt_b   = (const float*)d_in[19];
    const float* m_A_log  = (const float*)d_in[20];
    const float* m_D      = (const float*)d_in[21];
    const float* m_out_w  = (const float*)d_in[22];
    const float* m_norm_w = (const float*)d_in[23];
    const float* m_normf_w= (const float*)d_in[24];
    const float* w_out = (const float*)d_in[25];
    const float* b_out = (const float*)d_in[26];
    float* out = (float*)d_out;

    float* GF  = (float*)d_ws;                        // B*128
    float* P   = GF + (size_t)B * HDIM;               // 2*4*8*128
    float* PART= P + 2 * 4 * TTOK * HDIM;             // B*4*PARTSZ
    int* bcursor  = (int*)(PART + (size_t)B * 4 * PARTSZ); // 512 (dst bins)
    int* bcursor2 = bcursor + NBUCK;                  // 512 (src bins) — zeroed together
    int* count    = bcursor2 + NBUCK;                 // N
    int* starts   = count + N;                        // N+1 (padded to N+8)
    int* ssrc     = starts + N + 8;                   // E
    uint* pairbuf = (uint*)(ssrc + E);                // NBUCK*BCAP uints (dst bins, then src bins)
    float* PS2    = (float*)(pairbuf + (size_t)NBUCK * BCAP); // B*512*128 f32 partials (PS2T)
    ushort* AGG = (ushort*)PS2;                       // N*128 bf16 — ALIASES PS2 (AGG dead before final)
    ushort* XB0 = (ushort*)(PS2 + (size_t)NBUCK * 128 * 128); // N*128 bf16
    ushort* XB1 = XB0 + (size_t)N * HDIM;             // N*128 bf16

    const int NBB = (E + EPB - 1) / EPB;   // 512

    // ---- dst-bin + convert in one launch ----
    hipMemsetAsync(bcursor, 0, 2 * NBUCK * sizeof(int), stream);
    bin_conv_kernel<<<NBB + 2048, 256, 0, stream>>>(src, dst, bcursor, pairbuf, E,
                                                    x_in, XB0, N * 32);
    bucket_sort_kernel<<<NBUCK, 256, 0, stream>>>(pairbuf, bcursor, ssrc, starts, count, N);

    // ---- input GIN gather ∥ attn prep ∥ src-bin (pairbuf reused post-sort) ----
    gather_prep_kernel<<<2 + N / 16 + NBB, 256, 0, stream>>>(XB0, ssrc, starts, count, AGG,
                                                             vt, qkv_w, qkv_b, P,
                                                             src, dst, bcursor2, pairbuf, E);
    lin128_mfma_kernel<<<N / 128, 256, 0, stream>>>(AGG, w_in, b_in, nullptr, XB1);

    ushort* Xcur = XB1;
    ushort* Xnext = XB0;
    const int nAG = B * 4 + N / 16;   // 512 attn + 8192 gather = 8704 = 17*512
    for (int l = 0; l < 2; ++l) {
        attn_gather_kernel<<<nAG, 256, 0, stream>>>(Xcur, P + (size_t)l * 4 * TTOK * HDIM,
                                                    PART, ssrc, starts, count, AGG);
        mamba_kernel<<<B, 1024, 0, stream>>>(PART,
                                             qkv_w + (size_t)l * 128 * 384,
                                             qkv_b + (size_t)l * 384,
                                             ao_w + (size_t)l * 128 * 128,
                                             ao_b + (size_t)l * 128,
                                             m_in_w, m_conv_w, m_conv_b, m_x_w,
                                             m_dt_w, m_dt_b, m_A_log, m_D, m_out_w,
                                             m_norm_w, m_normf_w, GF);
        lin128_mfma_kernel<<<N / 128, 256, 0, stream>>>(AGG, gin_w + (size_t)l * 128 * 128,
                                                        gin_b + (size_t)l * 128, GF, Xnext);
        ushort* t = Xcur; Xcur = Xnext; Xnext = t;
    }

    // ---- final GIN + segment_sum: counts-MFMA partials (transposed) + fused reduce+mm ----
    final_count_kernel<<<NBUCK, 512, 0, stream>>>(Xcur, pairbuf, bcursor2, PS2);
    final_mm_kernel<<<B, 512, 0, stream>>>(PS2, w_out, b_out, out);

    (void)n_in; (void)out_size; (void)ws_size;
}

// Round 9
// 786.204 us; speedup vs baseline: 1.2237x; 1.0090x over previous
//
#include <hip/hip_runtime.h>

#define HDIM 128
#define TTOK 8
#define NPG 1024
#define NBUCK 512
#define BSHIFT 8
#define BCAP 5120
#define EPB 4096
#define PARTSZ 4160   // per (graph,part): 32*128 O + 32 m + 32 l

typedef unsigned short ushort;
typedef unsigned int uint;
typedef __attribute__((ext_vector_type(8))) short short8;
typedef __attribute__((ext_vector_type(4))) float f32x4;

__device__ __forceinline__ ushort f2bf(float f) {
    unsigned int x = __float_as_uint(f);
    return (ushort)((x + 0x7FFFu + ((x >> 16) & 1u)) >> 16);
}
__device__ __forceinline__ float blo(uint u) { return __uint_as_float(u << 16); }
__device__ __forceinline__ float bhi(uint u) { return __uint_as_float(u & 0xFFFF0000u); }
__device__ __forceinline__ uint pk(float a, float b) {
    return (uint)f2bf(a) | ((uint)f2bf(b) << 16);
}

// ================= dst-bin + src-bin + f32->bf16 convert, one launch =================
// blocks [0,512): dst-bin -> pairbuf; [512,1024): src-bin -> pairbuf2; [1024,3072): convert.
// Bin scatter is LDS counting-sorted first so global writes go out as contiguous
// per-bucket runs (R8 post-mortem: 4B random scatter was ~64 lines/wave-store).
__global__ __launch_bounds__(256) void bin_conv_kernel(const int* __restrict__ src,
    const int* __restrict__ dst, int* __restrict__ bcursor, uint* __restrict__ pairbuf,
    int* __restrict__ bcursor2, uint* __restrict__ pairbuf2, int E,
    const float* __restrict__ xin, ushort* __restrict__ outb, int n4)
{
    __shared__ int lcnt[NBUCK];
    __shared__ int lexcl[NBUCK];
    __shared__ int gbase[NBUCK];
    __shared__ uint lsorted[EPB];    // 16 KB
    __shared__ ushort lbkt[EPB];     // 8 KB
    int tid = threadIdx.x, b = blockIdx.x;
    if (b < 2 * NBUCK) {
        int mode = (b >= NBUCK) ? 1 : 0;
        int e0 = (mode ? b - NBUCK : b) * EPB;
        int* bc = mode ? bcursor2 : bcursor;
        uint* pb = mode ? pairbuf2 : pairbuf;
        for (int i = tid; i < NBUCK; i += 256) lcnt[i] = 0;
        __syncthreads();
        uint pkd[16];
        int bk[16], rk[16];
        #pragma unroll
        for (int i = 0; i < 16; ++i) {
            int e = e0 + i * 256 + tid;
            int s = (e < E) ? src[e] : 0;
            int d = (e < E) ? dst[e] : 0;
            int key = mode ? s : d;
            uint pay = mode ? (uint)(d >> 10) : (uint)s;
            if (e >= E) key = -1;
            int bb = key >> BSHIFT;
            bk[i] = bb;
            pkd[i] = ((uint)(key & 255) << 17) | pay;
            rk[i] = (key >= 0) ? atomicAdd(&lcnt[bb], 1) : 0;
        }
        __syncthreads();
        // inclusive scan of lcnt -> lexcl
        lexcl[tid] = lcnt[tid];
        lexcl[tid + 256] = lcnt[tid + 256];
        __syncthreads();
        for (int off = 1; off < NBUCK; off <<= 1) {
            int a0 = (tid >= off) ? lexcl[tid - off] : 0;
            int a1 = (tid + 256 >= off) ? lexcl[tid + 256 - off] : 0;
            __syncthreads();
            lexcl[tid] += a0; lexcl[tid + 256] += a1;
            __syncthreads();
        }
        for (int i = tid; i < NBUCK; i += 256) {
            int c = lcnt[i];
            gbase[i] = c ? atomicAdd(&bc[i], c) : 0;
        }
        __syncthreads();
        // reorder into bucket-contiguous runs in LDS
        #pragma unroll
        for (int i = 0; i < 16; ++i) {
            if (bk[i] >= 0) {
                int pos = lexcl[bk[i]] - lcnt[bk[i]] + rk[i];
                lsorted[pos] = pkd[i];
                lbkt[pos] = (ushort)bk[i];
            }
        }
        __syncthreads();
        // burst out: consecutive i within a run -> consecutive global addresses
        int total = lexcl[NBUCK - 1];
        for (int i = tid; i < total; i += 256) {
            int bb = lbkt[i];
            int slot = gbase[bb] + (i - (lexcl[bb] - lcnt[bb]));
            if (slot < BCAP) pb[(size_t)bb * BCAP + slot] = lsorted[i];
        }
    } else {
        for (int i = (b - 2 * NBUCK) * 256 + tid; i < n4; i += 2048 * 256) {
            float4 v = ((const float4*)xin)[i];
            uint2 o;
            o.x = pk(v.x, v.y); o.y = pk(v.z, v.w);
            ((uint2*)outb)[i] = o;
        }
    }
}

// ================= Pass B (dst-sort): one block per bucket; self-scans bucket counts =================
__global__ __launch_bounds__(256) void bucket_sort_kernel(const uint* __restrict__ pairbuf,
    const int* __restrict__ bcount,
    int* __restrict__ ssrc, int* __restrict__ starts, int* __restrict__ countn, int N)
{
    __shared__ int sc[NBUCK];
    __shared__ int lcount[256];
    __shared__ int lcur[256];
    __shared__ int lss[BCAP];   // 20 KB
    int b = blockIdx.x;
    int tid = threadIdx.x;
    sc[tid] = min(bcount[tid], BCAP);
    sc[tid + 256] = min(bcount[tid + 256], BCAP);
    lcount[tid] = 0;
    __syncthreads();
    for (int off = 1; off < NBUCK; off <<= 1) {
        int a0 = (tid >= off) ? sc[tid - off] : 0;
        int a1 = (tid + 256 >= off) ? sc[tid + 256 - off] : 0;
        __syncthreads();
        sc[tid] += a0; sc[tid + 256] += a1;
        __syncthreads();
    }
    int nb = min(bcount[b], BCAP);
    int base = sc[b] - nb;
    const uint* pp = pairbuf + (size_t)b * BCAP;
    for (int i = tid; i < nb; i += 256)
        atomicAdd(&lcount[(pp[i] >> 17) & 255], 1);
    __syncthreads();
    int v = lcount[tid];
    lcur[tid] = v;
    __syncthreads();
    for (int off = 1; off < 256; off <<= 1) {
        int t = (tid >= off) ? lcur[tid - off] : 0;
        __syncthreads();
        lcur[tid] += t;
        __syncthreads();
    }
    int excl = lcur[tid] - v;
    int node = b * 256 + tid;
    starts[node] = base + excl;
    countn[node] = v;
    __syncthreads();
    lcur[tid] = excl;
    __syncthreads();
    for (int i = tid; i < nb; i += 256) {
        uint p = pp[i];
        int pos = atomicAdd(&lcur[(p >> 17) & 255], 1);
        lss[pos] = (int)(p & 0x1FFFFu);
    }
    __syncthreads();
    for (int i = tid; i < nb; i += 256) ssrc[base + i] = lss[i];
    if (b == NBUCK - 1 && tid == 0) starts[N] = base + nb;
}

// ================= gather body: 16 nodes, 16 lanes each, 8-deep ILP =================
__device__ __forceinline__ void gather16_body(const ushort* __restrict__ XS,
    const int* __restrict__ ssrc, const int* __restrict__ starts,
    const int* __restrict__ count, ushort* __restrict__ AGG, int nbase, int tid)
{
    int g = tid >> 4, lane = tid & 15;
    int node = nbase + g;
    uint4 sv = *((const uint4*)(XS + (size_t)node * HDIM) + lane);
    float a0 = blo(sv.x), a1 = bhi(sv.x), a2 = blo(sv.y), a3 = bhi(sv.y);
    float a4 = blo(sv.z), a5 = bhi(sv.z), a6 = blo(sv.w), a7 = bhi(sv.w);
    int s0 = starts[node], cn = count[node];
    for (int j0 = 0; j0 < cn; j0 += 16) {
        int myid = (j0 + lane < cn) ? ssrc[s0 + j0 + lane] : 0;
        int m = min(16, cn - j0);
        int j = 0;
        for (; j + 7 < m; j += 8) {
            uint4 u[8];
            #pragma unroll
            for (int q = 0; q < 8; ++q) {
                int sidx = __shfl(myid, j + q, 16);
                u[q] = *((const uint4*)(XS + (size_t)sidx * HDIM) + lane);
            }
            #pragma unroll
            for (int q = 0; q < 8; ++q) {
                a0 += blo(u[q].x); a1 += bhi(u[q].x);
                a2 += blo(u[q].y); a3 += bhi(u[q].y);
                a4 += blo(u[q].z); a5 += bhi(u[q].z);
                a6 += blo(u[q].w); a7 += bhi(u[q].w);
            }
        }
        for (; j + 3 < m; j += 4) {
            uint4 u[4];
            #pragma unroll
            for (int q = 0; q < 4; ++q) {
                int sidx = __shfl(myid, j + q, 16);
                u[q] = *((const uint4*)(XS + (size_t)sidx * HDIM) + lane);
            }
            #pragma unroll
            for (int q = 0; q < 4; ++q) {
                a0 += blo(u[q].x); a1 += bhi(u[q].x);
                a2 += blo(u[q].y); a3 += bhi(u[q].y);
                a4 += blo(u[q].z); a5 += bhi(u[q].z);
                a6 += blo(u[q].w); a7 += bhi(u[q].w);
            }
        }
        for (; j < m; ++j) {
            int sidx = __shfl(myid, j, 16);
            uint4 ua = *((const uint4*)(XS + (size_t)sidx * HDIM) + lane);
            a0 += blo(ua.x); a1 += bhi(ua.x);
            a2 += blo(ua.y); a3 += bhi(ua.y);
            a4 += blo(ua.z); a5 += bhi(ua.z);
            a6 += blo(ua.w); a7 += bhi(ua.w);
        }
    }
    uint4 o;
    o.x = pk(a0, a1); o.y = pk(a2, a3); o.z = pk(a4, a5); o.w = pk(a6, a7);
    *((uint4*)(AGG + (size_t)node * HDIM) + lane) = o;
}

// ================= input-GIN gather ∥ attn-prep (one dispatch) =================
// blocks 0-1: attn P prep (long; scheduled first); [2, 2+8192): gather.
__global__ __launch_bounds__(256) void gather_prep_kernel(const ushort* __restrict__ XS,
    const int* __restrict__ ssrc, const int* __restrict__ starts,
    const int* __restrict__ count, ushort* __restrict__ AGG,
    const float* __restrict__ vt, const float* __restrict__ qkv_w,
    const float* __restrict__ qkv_b, float* __restrict__ P)
{
    __shared__ float vtl[TTOK][HDIM];
    __shared__ float q[TTOK][HDIM];
    int b = blockIdx.x, tid = threadIdx.x;
    if (b < 2) {
        int l = b;
        const float* vtp = vt + (size_t)l * TTOK * HDIM;
        const float* qw = qkv_w + (size_t)l * 128 * 384;
        const float* qb = qkv_b + (size_t)l * 384;
        float* Pp = P + (size_t)l * 4 * TTOK * HDIM;
        for (int i = tid; i < TTOK * HDIM; i += 256) vtl[i >> 7][i & 127] = vtp[i];
        __syncthreads();
        for (int i = tid; i < TTOK * HDIM; i += 256) {
            int t = i >> 7, j = i & 127;
            float acc = qb[j];
            for (int c = 0; c < 128; ++c) acc += vtl[t][c] * qw[c * 384 + j];
            q[t][j] = acc;
        }
        __syncthreads();
        const float scale = 0.17677669529663687f; // 1/sqrt(32)
        for (int i = tid; i < 4 * TTOK * HDIM; i += 256) {
            int h = i >> 10, t = (i >> 7) & 7, cc = i & 127;
            float acc = 0.f;
            for (int d = 0; d < 32; ++d)
                acc += qw[cc * 384 + 128 + h * 32 + d] * q[t][h * 32 + d];
            Pp[i] = acc * scale;
        }
    } else {
        gather16_body(XS, ssrc, starts, count, AGG, (b - 2) * 16, tid);
    }
}

// ================= attention body v3: 64-node tiles, ~25.2 KB LDS (St/P union) =================
__device__ __forceinline__ void attn_body(const ushort* __restrict__ X,
    const float* __restrict__ P, float* __restrict__ PART, int bp, int tid)
{
    __shared__ ushort Xl[64 * 128];    // 16 KB swizzled X tile (64 nodes)
    __shared__ float  StU[32 * 68];    // 8.5 KB union: prologue-P bf16 / scores f32 / exp-P bf16
    __shared__ float lm[32], ll[32], lalpha[32];
    ushort* PlU = (ushort*)StU;
    int b = bp >> 2, part = bp & 3;
    int wave = tid >> 6, lane = tid & 63;
    int m16 = lane & 15, quad = lane >> 4;

    for (int i = tid; i < 2048; i += 256) {
        float2 v = *(const float2*)(P + (size_t)i * 2);
        ((uint*)PlU)[i] = pk(v.x, v.y);
    }
    if (tid < 32) { lm[tid] = -1e30f; ll[tid] = 0.f; }
    __syncthreads();
    short8 aP[2][4];
    #pragma unroll
    for (int mt = 0; mt < 2; ++mt)
        #pragma unroll
        for (int kc = 0; kc < 4; ++kc)
            aP[mt][kc] = *(const short8*)&PlU[(mt * 16 + m16) * 128 + (kc * 4 + quad) * 8];
    __syncthreads();

    f32x4 oacc[2][2] = {};
    const uint4* xsg = (const uint4*)(X + (size_t)b * NPG * HDIM);

    for (int tt = 0; tt < 4; ++tt) {
        {
            const uint4* xs = xsg + (part * 4 + tt) * 1024;
            uint4* xl = (uint4*)Xl;
            for (int i = tid; i < 1024; i += 256) {
                int row = i >> 4, cc = i & 15;
                xl[row * 16 + (cc ^ (row & 15))] = xs[i];
            }
        }
        __syncthreads();
        {
            f32x4 sacc[2] = {};
            #pragma unroll
            for (int kc = 0; kc < 4; ++kc) {
                int node = wave * 16 + m16;
                short8 bx = *(const short8*)&Xl[node * 128 + (((kc * 4 + quad) ^ m16) << 3)];
                sacc[0] = __builtin_amdgcn_mfma_f32_16x16x32_bf16(aP[0][kc], bx, sacc[0], 0, 0, 0);
                sacc[1] = __builtin_amdgcn_mfma_f32_16x16x32_bf16(aP[1][kc], bx, sacc[1], 0, 0, 0);
            }
            #pragma unroll
            for (int mt = 0; mt < 2; ++mt)
                #pragma unroll
                for (int r = 0; r < 4; ++r)
                    StU[(mt * 16 + quad * 4 + r) * 68 + wave * 16 + m16] = sacc[mt][r];
        }
        __syncthreads();
        {
            int j = tid >> 3, g = tid & 7;
            const float* rowp = &StU[j * 68 + g * 8];
            float4 v0 = *(const float4*)(rowp);
            float4 v1 = *(const float4*)(rowp + 4);
            float mx = fmaxf(fmaxf(fmaxf(v0.x, v0.y), fmaxf(v0.z, v0.w)),
                             fmaxf(fmaxf(v1.x, v1.y), fmaxf(v1.z, v1.w)));
            mx = fmaxf(mx, __shfl_down(mx, 4, 8));
            mx = fmaxf(mx, __shfl_down(mx, 2, 8));
            mx = fmaxf(mx, __shfl_down(mx, 1, 8));
            mx = __shfl(mx, 0, 8);
            float mold = lm[j];
            float Mn = fmaxf(mold, mx);
            float alpha = __expf(mold - Mn);
            float p0 = __expf(v0.x - Mn), p1 = __expf(v0.y - Mn);
            float p2 = __expf(v0.z - Mn), p3 = __expf(v0.w - Mn);
            float p4 = __expf(v1.x - Mn), p5 = __expf(v1.y - Mn);
            float p6 = __expf(v1.z - Mn), p7 = __expf(v1.w - Mn);
            float s = ((p0 + p1) + (p2 + p3)) + ((p4 + p5) + (p6 + p7));
            s += __shfl_down(s, 4, 8);
            s += __shfl_down(s, 2, 8);
            s += __shfl_down(s, 1, 8);
            if (g == 0) {
                ll[j] = ll[j] * alpha + s;
                lm[j] = Mn;
                lalpha[j] = alpha;
            }
            __syncthreads();   // all St reads complete before exp-P overwrites the union
            uint4 u0;
            u0.x = pk(p0, p1); u0.y = pk(p2, p3); u0.z = pk(p4, p5); u0.w = pk(p6, p7);
            ((uint4*)PlU)[j * 8 + (g ^ (j & 7))] = u0;   // exp-P [32][64], chunk-swizzled
        }
        __syncthreads();
        {
            #pragma unroll
            for (int mt = 0; mt < 2; ++mt)
                #pragma unroll
                for (int r = 0; r < 4; ++r) {
                    float a = lalpha[mt * 16 + quad * 4 + r];
                    oacc[mt][0][r] *= a;
                    oacc[mt][1][r] *= a;
                }
            #pragma unroll
            for (int kc = 0; kc < 2; ++kc) {
                short8 ap2[2], bx[2];
                #pragma unroll
                for (int mt = 0; mt < 2; ++mt)
                    ap2[mt] = *(const short8*)&PlU[(mt * 16 + m16) * 64
                                                   + (((kc * 4 + quad) ^ (m16 & 7)) << 3)];
                #pragma unroll
                for (int ntl = 0; ntl < 2; ++ntl) {
                    int cf = (2 * wave + ntl) * 16 + m16;
                    int chi = cf >> 3, clo = cf & 7;
                    short8 v;
                    #pragma unroll
                    for (int jj = 0; jj < 8; ++jj) {
                        int row = kc * 32 + quad * 8 + jj;
                        v[jj] = (short)Xl[(row << 7) + ((chi ^ (row & 15)) << 3) + clo];
                    }
                    bx[ntl] = v;
                }
                #pragma unroll
                for (int mt = 0; mt < 2; ++mt)
                    #pragma unroll
                    for (int ntl = 0; ntl < 2; ++ntl)
                        oacc[mt][ntl] = __builtin_amdgcn_mfma_f32_16x16x32_bf16(
                            ap2[mt], bx[ntl], oacc[mt][ntl], 0, 0, 0);
            }
        }
        __syncthreads();
    }
    float* PB = PART + ((size_t)b * 4 + part) * PARTSZ;
    #pragma unroll
    for (int mt = 0; mt < 2; ++mt)
        #pragma unroll
        for (int r = 0; r < 4; ++r) {
            int j = mt * 16 + quad * 4 + r;
            PB[j * 128 + (2 * wave + 0) * 16 + m16] = oacc[mt][0][r];
            PB[j * 128 + (2 * wave + 1) * 16 + m16] = oacc[mt][1][r];
        }
    if (tid < 32) { PB[4096 + tid] = lm[tid]; PB[4128 + tid] = ll[tid]; }
}

// ================= combined attention ∥ gather (independent work, one dispatch) =================
__global__ __launch_bounds__(256) void attn_gather_kernel(const ushort* __restrict__ X,
    const float* __restrict__ P, float* __restrict__ PART,
    const int* __restrict__ ssrc, const int* __restrict__ starts,
    const int* __restrict__ count, ushort* __restrict__ AGG)
{
    int bp = blockIdx.x;
    if (bp % 17 == 0) {
        attn_body(X, P, PART, bp / 17, threadIdx.x);
    } else {
        int gidx = bp - bp / 17 - 1;
        gather16_body(X, ssrc, starts, count, AGG, gidx * 16, threadIdx.x);
    }
}

// ================= MFMA linear (bf16 in/out): XD = XS @ W + b [+ GF[row>>10]] =================
__global__ __launch_bounds__(256) void lin128_mfma_kernel(const ushort* __restrict__ XS,
    const float* __restrict__ W, const float* __restrict__ bias,
    const float* __restrict__ GF, ushort* __restrict__ XD)
{
    __shared__ ushort Xl[128 * 128];
    __shared__ ushort Wl[128 * 128];
    int tid = threadIdx.x;
    size_t r0 = (size_t)blockIdx.x * 128;
    {
        const uint4* xs = (const uint4*)(XS + r0 * HDIM);
        uint4* xl = (uint4*)Xl;
        for (int i = tid; i < 2048; i += 256) {
            int row = i >> 4, cc = i & 15;
            xl[row * 16 + (cc ^ (row & 15))] = xs[i];
        }
    }
    {
        uint4* wl = (uint4*)Wl;
        for (int i = tid; i < 2048; i += 256) {
            int n = i & 127, c = i >> 7;
            const float* wp = W + (size_t)(c * 8) * 128 + n;
            float w0 = wp[0], w1 = wp[128], w2 = wp[256], w3 = wp[384];
            float w4 = wp[512], w5 = wp[640], w6 = wp[768], w7 = wp[896];
            uint4 u;
            u.x = pk(w0, w1); u.y = pk(w2, w3); u.z = pk(w4, w5); u.w = pk(w6, w7);
            wl[n * 16 + (c ^ (n & 15))] = u;
        }
    }
    __syncthreads();
    int wave = tid >> 6;
    int lane = tid & 63;
    int m16 = lane & 15, quad = lane >> 4;
    const short8* Xf = (const short8*)Xl;
    const short8* Wf = (const short8*)Wl;
    short8 afr[2][4];
    #pragma unroll
    for (int rt = 0; rt < 2; ++rt)
        #pragma unroll
        for (int kc = 0; kc < 4; ++kc)
            afr[rt][kc] = Xf[(wave * 32 + rt * 16 + m16) * 16 + ((kc * 4 + quad) ^ m16)];
    int graph = (int)(r0 >> 10);
    #pragma unroll
    for (int ct = 0; ct < 8; ++ct) {
        int col = ct * 16 + m16;
        short8 bfr[4];
        #pragma unroll
        for (int kc = 0; kc < 4; ++kc)
            bfr[kc] = Wf[col * 16 + ((kc * 4 + quad) ^ m16)];
        f32x4 acc0 = {0.f, 0.f, 0.f, 0.f};
        f32x4 acc1 = {0.f, 0.f, 0.f, 0.f};
        #pragma unroll
        for (int kc = 0; kc < 4; ++kc) {
            acc0 = __builtin_amdgcn_mfma_f32_16x16x32_bf16(afr[0][kc], bfr[kc], acc0, 0, 0, 0);
            acc1 = __builtin_amdgcn_mfma_f32_16x16x32_bf16(afr[1][kc], bfr[kc], acc1, 0, 0, 0);
        }
        float add = bias[col] + (GF ? GF[(size_t)graph * HDIM + col] : 0.f);
        #pragma unroll
        for (int r = 0; r < 4; ++r) {
            XD[(r0 + wave * 32 + quad * 4 + r) * HDIM + col] = f2bf(acc0[r] + add);
            XD[(r0 + wave * 32 + 16 + quad * 4 + r) * HDIM + col] = f2bf(acc1[r] + add);
        }
    }
}

// ================= mamba (R5 layout: strided-per-thread = wave-coalesced weights) =================
__global__ __launch_bounds__(1024) void mamba_kernel(const float* __restrict__ PART,
    const float* __restrict__ qkv_w, const float* __restrict__ qkv_b,
    const float* __restrict__ ao_w, const float* __restrict__ ao_b,
    const float* __restrict__ in_w, const float* __restrict__ conv_w,
    const float* __restrict__ conv_b, const float* __restrict__ x_w,
    const float* __restrict__ dt_w, const float* __restrict__ dt_b,
    const float* __restrict__ A_log, const float* __restrict__ Dp,
    const float* __restrict__ out_w, const float* __restrict__ norm_w,
    const float* __restrict__ normf_w, float* __restrict__ GF)
{
    constexpr int I = 256, S = 16;
    __shared__ float R[32 * 132];
    __shared__ float wgt[4][32];
    __shared__ float inv[32];
    __shared__ float tok[TTOK][HDIM];
    __shared__ float hn[TTOK][HDIM];
    __shared__ float uu[TTOK][I];
    __shared__ float gg[TTOK][I];
    __shared__ float ssm[TTOK][40];
    __shared__ float yy[TTOK][I];
    int b = blockIdx.x, tid = threadIdx.x;

    const float* PB = PART + (size_t)b * 4 * PARTSZ;
    if (tid < 32) {
        int j = tid;
        float m0 = PB[4096 + j], m1 = PB[PARTSZ + 4096 + j];
        float m2 = PB[2 * PARTSZ + 4096 + j], m3 = PB[3 * PARTSZ + 4096 + j];
        float M = fmaxf(fmaxf(m0, m1), fmaxf(m2, m3));
        float w0 = __expf(m0 - M), w1 = __expf(m1 - M);
        float w2 = __expf(m2 - M), w3 = __expf(m3 - M);
        float L = w0 * PB[4128 + j] + w1 * PB[PARTSZ + 4128 + j]
                + w2 * PB[2 * PARTSZ + 4128 + j] + w3 * PB[3 * PARTSZ + 4128 + j];
        wgt[0][j] = w0; wgt[1][j] = w1; wgt[2][j] = w2; wgt[3][j] = w3;
        inv[j] = 1.f / L;
    }
    __syncthreads();
    #pragma unroll
    for (int it = 0; it < 4; ++it) {
        int idx = it * 1024 + tid;
        int j = idx >> 7, c = idx & 127;
        float v = wgt[0][j] * PB[idx] + wgt[1][j] * PB[PARTSZ + idx]
                + wgt[2][j] * PB[2 * PARTSZ + idx] + wgt[3][j] * PB[3 * PARTSZ + idx];
        R[j * 132 + c] = v * inv[j];
    }
    __syncthreads();
    {
        int t = tid >> 7, col = tid & 127;
        int h = col >> 5;
        const float* rp = &R[(h * 8 + t) * 132];
        const float* wp = qkv_w + 256 + col;
        float acc = qkv_b[256 + col];
        for (int c = 0; c < 128; c += 8) {
            float w[8];
            #pragma unroll
            for (int q = 0; q < 8; ++q) w[q] = wp[(size_t)(c + q) * 384];
            #pragma unroll
            for (int q = 0; q < 8; ++q) acc += rp[c + q] * w[q];
        }
        hn[t][col] = acc;
    }
    __syncthreads();
    {
        int t = tid >> 7, col = tid & 127;
        const float* hp = hn[t];
        const float* wp = ao_w + col;
        float acc = ao_b[col];
        for (int k = 0; k < 128; k += 8) {
            float w[8];
            #pragma unroll
            for (int q = 0; q < 8; ++q) w[q] = wp[(size_t)(k + q) * 128];
            #pragma unroll
            for (int q = 0; q < 8; ++q) acc += hp[k + q] * w[q];
        }
        tok[t][col] = acc;
    }
    __syncthreads();

    if (tid < 512) {
        int t = tid >> 6, lane = tid & 63;
        float v0 = tok[t][lane], v1 = tok[t][lane + 64];
        float s = v0 * v0 + v1 * v1;
        #pragma unroll
        for (int off = 32; off; off >>= 1) s += __shfl_down(s, off);
        s = __shfl(s, 0);
        float r = rsqrtf(s * (1.f / 128.f) + 1e-5f);
        hn[t][lane] = v0 * r * norm_w[lane];
        hn[t][lane + 64] = v1 * r * norm_w[lane + 64];
    }
    __syncthreads();
    {
        int j = tid & 511, tq = tid >> 9;
        float acc[4] = {0.f, 0.f, 0.f, 0.f};
        const float* wp = in_w + j;
        for (int c = 0; c < 128; c += 8) {
            float w[8];
            #pragma unroll
            for (int q = 0; q < 8; ++q) w[q] = wp[(size_t)(c + q) * 512];
            #pragma unroll
            for (int q = 0; q < 8; ++q) {
                float wq = w[q];
                #pragma unroll
                for (int k = 0; k < 4; ++k) acc[k] += hn[tq * 4 + k][c + q] * wq;
            }
        }
        if (j < 256) {
            #pragma unroll
            for (int k = 0; k < 4; ++k) uu[tq * 4 + k][j] = acc[k];
        } else {
            #pragma unroll
            for (int k = 0; k < 4; ++k) gg[tq * 4 + k][j - 256] = acc[k];
        }
    }
    __syncthreads();
    if (tid < 256) {
        int i = tid;
        float cw0 = conv_w[i * 4 + 0], cw1 = conv_w[i * 4 + 1];
        float cw2 = conv_w[i * 4 + 2], cw3 = conv_w[i * 4 + 3];
        float cb = conv_b[i];
        float uv[TTOK];
        #pragma unroll
        for (int t = 0; t < TTOK; ++t) uv[t] = uu[t][i];
        #pragma unroll
        for (int t = 0; t < TTOK; ++t) {
            float a = cw3 * uv[t] + cb;
            if (t >= 1) a += cw2 * uv[t - 1];
            if (t >= 2) a += cw1 * uv[t - 2];
            if (t >= 3) a += cw0 * uv[t - 3];
            float sg = 1.f / (1.f + __expf(-a));
            uu[t][i] = a * sg;
        }
    }
    __syncthreads();
    {
        int t = tid >> 7, j = tid & 127;
        if (j < 40) {
            float acc = 0.f;
            const float* wp = x_w + j;
            const float* up = uu[t];
            for (int c = 0; c < 256; c += 8) {
                float w[8];
                #pragma unroll
                for (int q = 0; q < 8; ++q) w[q] = wp[(size_t)(c + q) * 40];
                #pragma unroll
                for (int q = 0; q < 8; ++q) acc += up[c + q] * w[q];
            }
            ssm[t][j] = acc;
        }
    }
    __syncthreads();
    if (tid < 256) {
        int i = tid;
        float dw[8];
        #pragma unroll
        for (int r = 0; r < 8; ++r) dw[r] = dt_w[r * 256 + i];
        float dtbias = dt_b[i];
        float a[S], st[S];
        #pragma unroll
        for (int s = 0; s < S; ++s) { a[s] = -__expf(A_log[i * S + s]); st[s] = 0.f; }
        float Di = Dp[i];
        for (int t = 0; t < TTOK; ++t) {
            float d = dtbias;
            #pragma unroll
            for (int r = 0; r < 8; ++r) d += ssm[t][r] * dw[r];
            d = (d > 20.f) ? d : log1pf(__expf(d));
            float ut = uu[t][i];
            float du = d * ut;
            float y = 0.f;
            #pragma unroll
            for (int s = 0; s < S; ++s) {
                float dA = __expf(d * a[s]);
                st[s] = dA * st[s] + du * ssm[t][8 + s];
                y += st[s] * ssm[t][24 + s];
            }
            y += ut * Di;
            float g = gg[t][i];
            float sg = 1.f / (1.f + __expf(-g));
            yy[t][i] = y * g * sg;
        }
    }
    __syncthreads();
    {
        int t = tid >> 7, c = tid & 127;
        float acc = tok[t][c];
        const float* wp = out_w + c;
        const float* yp = yy[t];
        for (int i = 0; i < 256; i += 8) {
            float w[8];
            #pragma unroll
            for (int q = 0; q < 8; ++q) w[q] = wp[(size_t)(i + q) * 128];
            #pragma unroll
            for (int q = 0; q < 8; ++q) acc += yp[i + q] * w[q];
        }
        hn[t][c] = acc;
    }
    __syncthreads();
    if (tid < 512) {
        int t = tid >> 6, lane = tid & 63;
        float v0 = hn[t][lane], v1 = hn[t][lane + 64];
        float s = v0 * v0 + v1 * v1;
        #pragma unroll
        for (int off = 32; off; off >>= 1) s += __shfl_down(s, off);
        s = __shfl(s, 0);
        float r = rsqrtf(s * (1.f / 128.f) + 1e-5f);
        hn[t][lane] = v0 * r * normf_w[lane];
        hn[t][lane + 64] = v1 * r * normf_w[lane + 64];
    }
    __syncthreads();
    if (tid < 128) {
        float s = 0.f;
        #pragma unroll
        for (int t = 0; t < TTOK; ++t) s += hn[t][tid];
        GF[(size_t)b * HDIM + tid] = s * (1.f / TTOK);
    }
}

// ================= final: per-src-bucket u8 count histogram + MFMA counts@X =================
// Writes TRANSPOSED partials PS2T[g][bkt][c] so the reducer reads each graph contiguously.
__global__ __launch_bounds__(512) void final_count_kernel(const ushort* __restrict__ X,
    const uint* __restrict__ pairbuf, const int* __restrict__ bcount,
    float* __restrict__ PS2)
{
    __shared__ uint hist[128 * 66];     // u8 counts [graph][src/4], padded: 33 KB
    __shared__ ushort Xb[128 * 128];    // 32 KB swizzled half-tile
    int bkt = blockIdx.x, tid = threadIdx.x;
    for (int i = tid; i < 128 * 66; i += 512) hist[i] = 0u;
    __syncthreads();
    int nb = min(bcount[bkt], BCAP);
    const uint* pp = pairbuf + (size_t)bkt * BCAP;
    for (int i = tid; i < nb; i += 512) {
        uint p = pp[i];
        int g = (int)(p & 0x1FFFFu);
        int s = (int)((p >> 17) & 255);
        atomicAdd(&hist[g * 66 + (s >> 2)], 1u << ((s & 3) * 8));
    }
    if (tid < 256) {                          // self term
        int g = bkt >> 2;
        atomicAdd(&hist[g * 66 + (tid >> 2)], 1u << ((tid & 3) * 8));
    }
    int wave = tid >> 6, lane = tid & 63;
    int m16 = lane & 15, quad = lane >> 4;
    int grow = wave * 16 + m16;
    f32x4 acc[8] = {};
    for (int half = 0; half < 2; ++half) {
        __syncthreads();
        {
            const uint4* xs = (const uint4*)(X + ((size_t)bkt * 256 + half * 128) * HDIM);
            uint4* xl = (uint4*)Xb;
            for (int i = tid; i < 2048; i += 512) {
                int row = i >> 4, cc = i & 15;
                xl[row * 16 + (cc ^ (row & 15))] = xs[i];
            }
        }
        __syncthreads();
        #pragma unroll
        for (int kc = 0; kc < 4; ++kc) {
            int s0 = half * 128 + kc * 32 + quad * 8;
            uint w0 = hist[grow * 66 + (s0 >> 2)];
            uint w1 = hist[grow * 66 + (s0 >> 2) + 1];
            short8 afr;
            ((uint*)&afr)[0] = pk((float)(w0 & 255u), (float)((w0 >> 8) & 255u));
            ((uint*)&afr)[1] = pk((float)((w0 >> 16) & 255u), (float)(w0 >> 24));
            ((uint*)&afr)[2] = pk((float)(w1 & 255u), (float)((w1 >> 8) & 255u));
            ((uint*)&afr)[3] = pk((float)((w1 >> 16) & 255u), (float)(w1 >> 24));
            #pragma unroll
            for (int ct = 0; ct < 8; ++ct) {
                int n = ct * 16 + m16;
                int chi = n >> 3, clo = n & 7;
                short8 bx;
                #pragma unroll
                for (int j = 0; j < 8; ++j) {
                    int k = kc * 32 + quad * 8 + j;
                    bx[j] = (short)Xb[(k << 7) + ((chi ^ (k & 15)) << 3) + clo];
                }
                acc[ct] = __builtin_amdgcn_mfma_f32_16x16x32_bf16(afr, bx, acc[ct], 0, 0, 0);
            }
        }
    }
    // transposed write: PS2T[g][bkt][c], g = wave*16+quad*4+r, c = ct*16+m16
    #pragma unroll
    for (int ct = 0; ct < 8; ++ct) {
        int n = ct * 16 + m16;
        #pragma unroll
        for (int r = 0; r < 4; ++r)
            PS2[(size_t)(wave * 16 + quad * 4 + r) * (NBUCK * 128)
                + (size_t)bkt * 128 + n] = acc[ct][r];
    }
}

// ================= final: contiguous reduce over buckets + tiny matmul (one block/graph) =================
__global__ __launch_bounds__(512) void final_mm_kernel(const float* __restrict__ PS2,
    const float* __restrict__ w_out, const float* __restrict__ b_out,
    float* __restrict__ out)
{
    __shared__ float red[4][128];
    __shared__ float Sm[HDIM];
    int b = blockIdx.x, tid = threadIdx.x;
    int c = tid & 127, q = tid >> 7;
    const float* base = PS2 + (size_t)b * (NBUCK * 128) + c;
    float s0 = 0.f, s1 = 0.f, s2 = 0.f, s3 = 0.f;
    int k0 = q * 128;
    for (int k = k0; k < k0 + 128; k += 4) {
        s0 += base[(size_t)(k + 0) * 128];
        s1 += base[(size_t)(k + 1) * 128];
        s2 += base[(size_t)(k + 2) * 128];
        s3 += base[(size_t)(k + 3) * 128];
    }
    red[q][c] = (s0 + s1) + (s2 + s3);
    __syncthreads();
    if (tid < 128) {
        Sm[tid] = (red[0][tid] + red[1][tid]) + (red[2][tid] + red[3][tid]);
    }
    __syncthreads();
    if (tid < 128) {
        float acc = 1024.f * b_out[tid];
        for (int k = 0; k < 128; ++k) acc += Sm[k] * w_out[k * 128 + tid];
        out[(size_t)b * HDIM + tid] = acc;
    }
}

extern "C" void kernel_launch(void* const* d_in, const int* in_sizes, int n_in,
                              void* d_out, int out_size, void* d_ws, size_t ws_size,
                              hipStream_t stream)
{
    const int N = in_sizes[0] / HDIM;      // 131072
    const int E = in_sizes[1] / 2;         // 2097152
    const int B = N >> 10;                 // 128 graphs

    const float* x_in  = (const float*)d_in[0];
    const int*   src   = (const int*)d_in[1];
    const int*   dst   = src + E;
    const float* w_in  = (const float*)d_in[5];
    const float* b_in  = (const float*)d_in[6];
    const float* gin_w = (const float*)d_in[7];
    const float* gin_b = (const float*)d_in[8];
    const float* vt    = (const float*)d_in[9];
    const float* qkv_w = (const float*)d_in[10];
    const float* qkv_b = (const float*)d_in[11];
    const float* ao_w  = (const float*)d_in[12];
    const float* ao_b  = (const float*)d_in[13];
    const float* m_in_w   = (const float*)d_in[14];
    const float* m_conv_w = (const float*)d_in[15];
    const float* m_conv_b = (const float*)d_in[16];
    const float* m_x_w    = (const float*)d_in[17];
    const float* m_dt_w   = (const float*)d_in[18];
    const float* m_dt_b   = (const float*)d_in[19];
    const float* m_A_log  = (const float*)d_in[20];
    const float* m_D      = (const float*)d_in[21];
    const float* m_out_w  = (const float*)d_in[22];
    const float* m_norm_w = (const float*)d_in[23];
    const float* m_normf_w= (const float*)d_in[24];
    const float* w_out = (const float*)d_in[25];
    const float* b_out = (const float*)d_in[26];
    float* out = (float*)d_out;

    float* GF  = (float*)d_ws;                        // B*128
    float* P   = GF + (size_t)B * HDIM;               // 2*4*8*128
    float* PART= P + 2 * 4 * TTOK * HDIM;             // B*4*PARTSZ
    int* bcursor  = (int*)(PART + (size_t)B * 4 * PARTSZ); // 512 (dst bins)
    int* bcursor2 = bcursor + NBUCK;                  // 512 (src bins) — zeroed together
    int* count    = bcursor2 + NBUCK;                 // N
    int* starts   = count + N;                        // N+1 (padded to N+8)
    int* ssrc     = starts + N + 8;                   // E
    uint* pairbuf  = (uint*)(ssrc + E);               // NBUCK*BCAP uints (dst bins)
    uint* pairbuf2 = pairbuf + (size_t)NBUCK * BCAP;  // NBUCK*BCAP uints (src bins)
    float* PS2    = (float*)(pairbuf2 + (size_t)NBUCK * BCAP); // B*512*128 f32 partials (PS2T)
    ushort* AGG = (ushort*)PS2;                       // N*128 bf16 — ALIASES PS2 (AGG dead before final)
    ushort* XB0 = (ushort*)(PS2 + (size_t)NBUCK * 128 * 128); // N*128 bf16
    ushort* XB1 = XB0 + (size_t)N * HDIM;             // N*128 bf16

    // ---- dst-bin + src-bin + convert in one launch ----
    hipMemsetAsync(bcursor, 0, 2 * NBUCK * sizeof(int), stream);
    bin_conv_kernel<<<2 * NBUCK + 2048, 256, 0, stream>>>(src, dst, bcursor, pairbuf,
                                                          bcursor2, pairbuf2, E,
                                                          x_in, XB0, N * 32);
    bucket_sort_kernel<<<NBUCK, 256, 0, stream>>>(pairbuf, bcursor, ssrc, starts, count, N);

    // ---- input GIN gather ∥ attn prep ----
    gather_prep_kernel<<<2 + N / 16, 256, 0, stream>>>(XB0, ssrc, starts, count, AGG,
                                                       vt, qkv_w, qkv_b, P);
    lin128_mfma_kernel<<<N / 128, 256, 0, stream>>>(AGG, w_in, b_in, nullptr, XB1);

    ushort* Xcur = XB1;
    ushort* Xnext = XB0;
    const int nAG = B * 4 + N / 16;   // 512 attn + 8192 gather = 8704 = 17*512
    for (int l = 0; l < 2; ++l) {
        attn_gather_kernel<<<nAG, 256, 0, stream>>>(Xcur, P + (size_t)l * 4 * TTOK * HDIM,
                                                    PART, ssrc, starts, count, AGG);
        mamba_kernel<<<B, 1024, 0, stream>>>(PART,
                                             qkv_w + (size_t)l * 128 * 384,
                                             qkv_b + (size_t)l * 384,
                                             ao_w + (size_t)l * 128 * 128,
                                             ao_b + (size_t)l * 128,
                                             m_in_w, m_conv_w, m_conv_b, m_x_w,
                                             m_dt_w, m_dt_b, m_A_log, m_D, m_out_w,
                                             m_norm_w, m_normf_w, GF);
        lin128_mfma_kernel<<<N / 128, 256, 0, stream>>>(AGG, gin_w + (size_t)l * 128 * 128,
                                                        gin_b + (size_t)l * 128, GF, Xnext);
        ushort* t = Xcur; Xcur = Xnext; Xnext = t;
    }

    // ---- final GIN + segment_sum: counts-MFMA partials (transposed) + fused reduce+mm ----
    final_count_kernel<<<NBUCK, 512, 0, stream>>>(Xcur, pairbuf2, bcursor2, PS2);
    final_mm_kernel<<<B, 512, 0, stream>>>(PS2, w_out, b_out, out);

    (void)n_in; (void)out_size; (void)ws_size;
}